// Round 7
// baseline (39646.274 us; speedup 1.0000x reference)
//
#include <hip/hip_runtime.h>
#include <cstdint>

// ---------------------------------------------------------------------------
// 3-layer LSTM (B=32, T=1024, H=I=512), PyTorch gate order (i,f,g,o).
//  - x_proj GEMMs: split-bf16 MFMA (A regions [hi|hi|lo], B regions [hi|lo|hi]
//    over K'=1536) -> fp32-class accuracy at bf16 MFMA rate.
//  - Recurrence: round-4 scheme (placement-INDEPENDENT, verified 3.8e-6):
//    W_hh split-bf16 in registers, h exchanged via st with per-instruction
//    device-coherent sc0sc1 loads/stores (no threadfence/acquire cache
//    maintenance). Rounds 5/6 failed because they bet correctness on the
//    UNDEFINED workgroup->XCD mapping (guide G16); that bet is reverted.
//    Contention fix vs round 4 (7us/step was poll contention: 256 waves
//    hammering 4 flag lines): 32 WGs x 512 thr, 32 flags on 2 lines,
//    wave-0-only polling -> 8x fewer pollers, half the flag lines.
//  - Time chunked CT=256: G buffer 64MiB reused; c persisted in global.
// ---------------------------------------------------------------------------

typedef unsigned short u16;
typedef short short8 __attribute__((ext_vector_type(8)));
typedef unsigned short ushort8 __attribute__((ext_vector_type(8)));
typedef float f32x4 __attribute__((ext_vector_type(4)));

#define NB 32
#define NT 1024
#define NH 512
#define N4H 2048
#define KS 1024   // stored row: [hi(512) | lo(512)] bf16
#define CT 256    // time chunk
#define MROWS (NB * NT)

__device__ __forceinline__ u16 f2bf(float f) {
  uint32_t u = __float_as_uint(f);
  uint32_t r = (u + 0x7fffu + ((u >> 16) & 1u)) >> 16;
  return (u16)r;
}
__device__ __forceinline__ float bf2f(u16 h) {
  return __uint_as_float((uint32_t)h << 16);
}
__device__ __forceinline__ float sigm(float x) { return 1.f / (1.f + __expf(-x)); }
__device__ __forceinline__ float tanh_s(float x) {
  float a = fabsf(x);
  float e = __expf(-2.f * a);
  float t = (1.f - e) / (1.f + e);
  return copysignf(t, x);
}

__device__ __forceinline__ void gload_lds16(const void* g, void* l) {
  __builtin_amdgcn_global_load_lds(
      (const __attribute__((address_space(1))) unsigned int*)g,
      (__attribute__((address_space(3))) unsigned int*)l, 16, 0, 0);
}

// --- per-instruction device-coherent (IC-level) accessors ---
__device__ __forceinline__ void ld16_sc(const u16* p, uint4& d) {
  asm volatile("global_load_dwordx4 %0, %1, off sc0 sc1" : "=v"(d) : "v"(p));
}
__device__ __forceinline__ unsigned ld_flag_sc(const unsigned* p) {
  unsigned r;
  asm volatile("global_load_dword %0, %1, off sc0 sc1\n\ts_waitcnt vmcnt(0)"
               : "=v"(r) : "v"(p) : "memory");
  return r;
}
__device__ __forceinline__ void st16b_sc(u16* p, unsigned v) {
  asm volatile("global_store_short %0, %1, off sc0 sc1" :: "v"(p), "v"(v) : "memory");
}
__device__ __forceinline__ void st32b_sc(unsigned* p, unsigned v) {
  asm volatile("global_store_dword %0, %1, off sc0 sc1" :: "v"(p), "v"(v) : "memory");
}

// X [32,4,1024,128] f32 -> st[n=b*1024+t][hi(512)|lo(512)] bf16
__global__ void k_gather_x(const float* __restrict__ X, u16* __restrict__ st) {
  int64_t i = (int64_t)blockIdx.x * 256 + threadIdx.x;  // 16,777,216
  int k = (int)(i & 511);
  int t = (int)((i >> 9) & 1023);
  int b = (int)(i >> 19);
  int c = k >> 7, f = k & 127;
  float v = X[(((int64_t)(b * 4 + c) * 1024 + t) << 7) + f];
  u16 hi = f2bf(v);
  u16 lo = f2bf(v - bf2f(hi));
  int64_t n = (int64_t)b * 1024 + t;
  st[n * KS + k] = hi;
  st[n * KS + 512 + k] = lo;
}

// W [2048,512] f32 -> Wp[2048][hi(512)|lo(512)] bf16
__global__ void k_split_w(const float* __restrict__ W, u16* __restrict__ Wp) {
  int i = blockIdx.x * 256 + threadIdx.x;  // 1,048,576
  int r = i >> 9, k = i & 511;
  float v = W[i];
  u16 hi = f2bf(v);
  u16 lo = f2bf(v - bf2f(hi));
  Wp[r * KS + k] = hi;
  Wp[r * KS + 512 + k] = lo;
}

__global__ void k_bias(const float* __restrict__ bi, const float* __restrict__ bh,
                       float* __restrict__ bo) {
  int i = blockIdx.x * 256 + threadIdx.x;
  if (i < N4H) bo[i] = bi[i] + bh[i];
}

// G[b*CT+dt][2048] = st[b*1024+t0+dt][:] * Wp^T + bias   (split-bf16, K'=1536)
// 128x128 tile, BK=64, 4 waves 2x2, global_load_lds staging (m97 structure).
__launch_bounds__(256, 2)
__global__ void k_xproj(const u16* __restrict__ A, const u16* __restrict__ Wp,
                        const float* __restrict__ bias, float* __restrict__ G,
                        int t0) {
  __shared__ u16 As[128 * 64];
  __shared__ u16 Bs[128 * 64];
  const int tid = threadIdx.x;
  const int lane = tid & 63;
  const int wv = tid >> 6;
  const int wm = wv & 1, wn = wv >> 1;
  const int ntile = blockIdx.x & 15;
  const int mtile = blockIdx.x >> 4;          // 0..63
  const int b = mtile >> 1;
  const int dt0 = (mtile & 1) << 7;
  const int64_t arow0 = (int64_t)b * NT + t0 + dt0;   // global st row
  const int grow0 = mtile * 128;                      // G chunk row
  const int brow0 = ntile * 128;

  f32x4 acc[4][4];
#pragma unroll
  for (int m = 0; m < 4; ++m)
#pragma unroll
    for (int n = 0; n < 4; ++n) acc[m][n] = (f32x4){0.f, 0.f, 0.f, 0.f};

  const int srow = tid >> 3;       // 0..31
  const int scol = (tid & 7) * 8;  // elements; *2B = lane-linear 16B LDS dma

  for (int kt = 0; kt < 24; ++kt) {
    const int r = kt >> 3;
    const int abase = ((r == 2) ? 512 : 0) + ((kt & 7) << 6);  // A: hi,hi,lo
    const int bbase = ((r == 1) ? 512 : 0) + ((kt & 7) << 6);  // B: hi,lo,hi
#pragma unroll
    for (int i = 0; i < 4; ++i) {
      int row = srow + i * 32;
      int e = row * 64 + scol;
      gload_lds16(A + (arow0 + row) * KS + abase + scol, As + e);
      gload_lds16(Wp + (int64_t)(brow0 + row) * KS + bbase + scol, Bs + e);
    }
    __syncthreads();
#pragma unroll
    for (int kk = 0; kk < 2; ++kk) {
      const int krow = kk * 32 + (lane >> 4) * 8;
      short8 af[4], bf[4];
#pragma unroll
      for (int m = 0; m < 4; ++m)
        af[m] = *(const short8*)&As[(wm * 64 + m * 16 + (lane & 15)) * 64 + krow];
#pragma unroll
      for (int n = 0; n < 4; ++n)
        bf[n] = *(const short8*)&Bs[(wn * 64 + n * 16 + (lane & 15)) * 64 + krow];
#pragma unroll
      for (int m = 0; m < 4; ++m)
#pragma unroll
        for (int n = 0; n < 4; ++n)
          acc[m][n] = __builtin_amdgcn_mfma_f32_16x16x32_bf16(af[m], bf[n], acc[m][n], 0, 0, 0);
    }
    __syncthreads();
  }

  // C/D: col = lane&15, row = (lane>>4)*4 + j  [m89-verified]
  const int cb = lane & 15;
  const int rb = (lane >> 4) * 4;
#pragma unroll
  for (int m = 0; m < 4; ++m) {
#pragma unroll
    for (int n = 0; n < 4; ++n) {
      const int grow = grow0 + wm * 64 + m * 16 + rb;
      const int gcol = brow0 + wn * 64 + n * 16 + cb;
      const float bv = bias[gcol];
#pragma unroll
      for (int j = 0; j < 4; ++j)
        G[(int64_t)(grow + j) * N4H + gcol] = acc[m][n][j] + bv;
    }
  }
}

// ---------------------------------------------------------------------------
// Recurrent chunk. 32 WGs x 512 thr (8 waves), placement-independent.
// WG wg owns units wg*16..wg*16+15 (x4 gates = 64 gate rows), all 32 batches.
// Wave wv: mq=wv&3 (unit-quad), nt=wv>>2 (batch-half). Lane (q=lane>>4,
// cb=lane&15): acc[j] = gate j of unit (wg*16 + mq*4 + q), batch (nt*16+cb).
// Every (batch,unit) owned by exactly one lane. VGPR (~164) forces 1 WG/CU;
// 32 WGs <= 256 CUs are always co-resident -- no placement assumption.
// Barrier: 32 flags (2 cachelines), sc0sc1; ONLY wave 0 polls, other waves
// wait at __syncthreads (round-4's 7us/step was 256-wave poll contention).
// ---------------------------------------------------------------------------
__launch_bounds__(512, 1)
__global__ void k_lstm(const float* __restrict__ Whh, const float* __restrict__ G,
                       u16* __restrict__ st, float* __restrict__ cbuf,
                       unsigned* __restrict__ flags, int t0, unsigned base) {
  const int tid = threadIdx.x;
  const int lane = tid & 63;
  const int wv = tid >> 6;        // 0..7
  const int mq = wv & 3;          // unit-quad within WG
  const int nt = wv >> 2;         // batch-half
  const int wg = blockIdx.x;      // 0..31
  const int q = lane >> 4;        // 0..3
  const int cb = lane & 15;

  // --- stage this lane's 32 W_hh frags (split bf16) into registers ---
  short8 whi[16], wlo[16];
  {
    const int tr = lane & 15;                  // A-row within 16x16 tile
    const int gate = tr & 3;
    const int64_t R = (int64_t)gate * 512 + (wg * 16 + mq * 4 + (tr >> 2));
    const float* wsrc = Whh + R * 512 + q * 8;
#pragma unroll
    for (int kk = 0; kk < 16; ++kk) {
      float4 a = *(const float4*)(wsrc + kk * 32);
      float4 b = *(const float4*)(wsrc + kk * 32 + 4);
      float v[8] = {a.x, a.y, a.z, a.w, b.x, b.y, b.z, b.w};
      ushort8 hi8, lo8;
#pragma unroll
      for (int e = 0; e < 8; ++e) {
        u16 h = f2bf(v[e]);
        hi8[e] = h;
        lo8[e] = f2bf(v[e] - bf2f(h));
      }
      whi[kk] = (short8)hi8;
      wlo[kk] = (short8)lo8;
    }
  }

  const int bat = nt * 16 + cb;          // this lane's batch
  const int u = wg * 16 + mq * 4 + q;    // this lane's unit
  float cst = (t0 > 0) ? cbuf[bat * NH + u] : 0.f;

  for (int s = 0; s < CT; ++s) {
    const int ts = t0 + s;

    // G loads: plain cached reads, independent of the barrier -> issue first
    const float* gp = G + ((int64_t)bat * CT + s) * N4H + u;
    float g0 = gp[0], g1 = gp[512], g2 = gp[1024], g3 = gp[1536];

    f32x4 acc0 = {0.f, 0.f, 0.f, 0.f};
    f32x4 acc1 = {0.f, 0.f, 0.f, 0.f};
    f32x4 acc2 = {0.f, 0.f, 0.f, 0.f};

    if (ts > 0) {
      if (s > 0) {  // wait until all 32 WGs published h(ts-1)
        if (wv == 0) {
          const unsigned tgt = base + (unsigned)s;
          int gd = 0;
          for (;;) {
            unsigned f = ld_flag_sc(flags + (lane & 31));
            if (__all((int)(f >= tgt))) break;
            __builtin_amdgcn_s_sleep(1);
            if (++gd > (1 << 18)) break;  // anomaly: fail fast to wrong output
          }
        }
        __syncthreads();
      }
      // h frags: coherent (IC) loads, issued in batch, one counted wait
      const u16* hb = st + ((int64_t)bat * NT + (ts - 1)) * KS + q * 8;
      uint4 hh[16], hl[16];
#pragma unroll
      for (int kk = 0; kk < 16; ++kk) {
        ld16_sc(hb + kk * 32, hh[kk]);
        ld16_sc(hb + 512 + kk * 32, hl[kk]);
      }
      asm volatile("s_waitcnt vmcnt(0)" ::: "memory");
      __builtin_amdgcn_sched_barrier(0);  // rule #18: keep MFMA after the wait
#pragma unroll
      for (int kk = 0; kk < 16; ++kk) {
        short8 hhv = __builtin_bit_cast(short8, hh[kk]);
        short8 hlv = __builtin_bit_cast(short8, hl[kk]);
        acc0 = __builtin_amdgcn_mfma_f32_16x16x32_bf16(whi[kk], hhv, acc0, 0, 0, 0);
        acc1 = __builtin_amdgcn_mfma_f32_16x16x32_bf16(whi[kk], hlv, acc1, 0, 0, 0);
        acc2 = __builtin_amdgcn_mfma_f32_16x16x32_bf16(wlo[kk], hhv, acc2, 0, 0, 0);
      }
    }

    float ip = (acc0[0] + acc1[0] + acc2[0]) + g0;
    float fp = (acc0[1] + acc1[1] + acc2[1]) + g1;
    float gg = (acc0[2] + acc1[2] + acc2[2]) + g2;
    float op = (acc0[3] + acc1[3] + acc2[3]) + g3;
    float i_s = sigm(ip), f_s = sigm(fp), g_t = tanh_s(gg), o_s = sigm(op);
    cst = f_s * cst + i_s * g_t;
    float h = o_s * tanh_s(cst);

    u16 hhi = f2bf(h);
    u16 hlo = f2bf(h - bf2f(hhi));
    u16* hp = st + ((int64_t)bat * NT + ts) * KS + u;
    st16b_sc(hp, (unsigned)hhi);
    st16b_sc(hp + 512, (unsigned)hlo);
    asm volatile("s_waitcnt vmcnt(0)" ::: "memory");  // h device-visible
    __syncthreads();                                   // all 8 waves done
    if (tid == 0)
      st32b_sc(flags + wg, base + (unsigned)s + 1);
  }

  cbuf[bat * NH + u] = cst;
}

// out[32,80] = (hi+lo of st[:,1023,:]) @ W_out^T + b_out
__global__ void k_final(const u16* __restrict__ st, const float* __restrict__ Wout,
                        const float* __restrict__ bout, float* __restrict__ out) {
  const int b = blockIdx.x;
  const int o = threadIdx.x;
  if (o >= 80) return;
  const u16* hp = st + ((int64_t)b * NT + (NT - 1)) * KS;
  float acc = bout[o];
  for (int k = 0; k < 512; ++k)
    acc += (bf2f(hp[k]) + bf2f(hp[512 + k])) * Wout[o * 512 + k];
  out[b * 80 + o] = acc;
}

extern "C" void kernel_launch(void* const* d_in, const int* in_sizes, int n_in,
                              void* d_out, int out_size, void* d_ws, size_t ws_size,
                              hipStream_t stream) {
  const float* X = (const float*)d_in[0];
  const float* Wih[3] = {(const float*)d_in[1], (const float*)d_in[5], (const float*)d_in[9]};
  const float* Whh[3] = {(const float*)d_in[2], (const float*)d_in[6], (const float*)d_in[10]};
  const float* bih[3] = {(const float*)d_in[3], (const float*)d_in[7], (const float*)d_in[11]};
  const float* bhh[3] = {(const float*)d_in[4], (const float*)d_in[8], (const float*)d_in[12]};
  const float* Wout = (const float*)d_in[13];
  const float* bout = (const float*)d_in[14];
  float* out = (float*)d_out;

  char* ws = (char*)d_ws;
  size_t off = 0;
  auto alloc = [&](size_t bytes) {
    char* p = ws + off;
    off = (off + bytes + 255) & ~(size_t)255;
    return p;
  };
  u16* st = (u16*)alloc((size_t)MROWS * KS * 2);          // 64 MiB
  float* G = (float*)alloc((size_t)NB * CT * N4H * 4);    // 64 MiB
  u16* Wp[3];
  for (int l = 0; l < 3; ++l) Wp[l] = (u16*)alloc((size_t)N4H * KS * 2);  // 4 MiB each
  float* bias[3];
  for (int l = 0; l < 3; ++l) bias[l] = (float*)alloc(N4H * 4);
  float* cbuf = (float*)alloc(NB * NH * 4);               // 64 KiB
  unsigned* flags = (unsigned*)alloc(32 * 4);
  // total ~140.4 MiB

  hipMemsetAsync(flags, 0, 32 * 4, stream);
  k_gather_x<<<65536, 256, 0, stream>>>(X, st);
  for (int l = 0; l < 3; ++l) {
    k_split_w<<<4096, 256, 0, stream>>>(Wih[l], Wp[l]);
    k_bias<<<8, 256, 0, stream>>>(bih[l], bhh[l], bias[l]);
  }

  for (int l = 0; l < 3; ++l) {
    for (int c = 0; c < NT / CT; ++c) {
      const int t0 = c * CT;
      const unsigned base = (unsigned)(l * 4 + c) * CT;
      k_xproj<<<1024, 256, 0, stream>>>(st, Wp[l], bias[l], G, t0);
      k_lstm<<<32, 512, 0, stream>>>(Whh[l], G, st, cbuf, flags, t0, base);
    }
  }

  k_final<<<32, 128, 0, stream>>>(st, Wout, bout, out);
}

// Round 8
// 24530.634 us; speedup vs baseline: 1.6162x; 1.6162x over previous
//
#include <hip/hip_runtime.h>
#include <cstdint>

// ---------------------------------------------------------------------------
// 3-layer LSTM (B=32, T=1024, H=I=512), PyTorch gate order (i,f,g,o).
//  - x_proj GEMMs: split-bf16 MFMA (A regions [hi|hi|lo], B regions [hi|lo|hi]
//    over K'=1536) -> fp32-class accuracy at bf16 MFMA rate.
//  - Recurrence: round-4 structure (64 WGs x 256 thr, placement-independent,
//    verified 3.8e-6): W_hh split-bf16 in registers, sc0sc1 h-stores + flag
//    barrier with all-wave polling.
//    NEW vs round 4: h-LOADS are plain cached. After the poll succeeds, ONE
//    agent-scope acquire (-> buffer_inv sc1, clean-L2 tag clear) makes the
//    freshly-published h lines safe to read through L1/L2. Round-4/7 profile
//    showed the step was bounded by per-CU sc0sc1 load issue (16B IC round
//    trips, 128-256KB/CU/step); cached loads turn the 2x-redundant wave reads
//    and cross-WG reads into XCD-L2 hits (~64KB distinct IC fill per XCD).
//  - Time chunked CT=256: G buffer 64MiB reused; c persisted in global.
// ---------------------------------------------------------------------------

typedef unsigned short u16;
typedef short short8 __attribute__((ext_vector_type(8)));
typedef unsigned short ushort8 __attribute__((ext_vector_type(8)));
typedef float f32x4 __attribute__((ext_vector_type(4)));

#define NB 32
#define NT 1024
#define NH 512
#define N4H 2048
#define KS 1024   // stored row: [hi(512) | lo(512)] bf16
#define CT 256    // time chunk
#define MROWS (NB * NT)

__device__ __forceinline__ u16 f2bf(float f) {
  uint32_t u = __float_as_uint(f);
  uint32_t r = (u + 0x7fffu + ((u >> 16) & 1u)) >> 16;
  return (u16)r;
}
__device__ __forceinline__ float bf2f(u16 h) {
  return __uint_as_float((uint32_t)h << 16);
}
__device__ __forceinline__ float sigm(float x) { return 1.f / (1.f + __expf(-x)); }
__device__ __forceinline__ float tanh_s(float x) {
  float a = fabsf(x);
  float e = __expf(-2.f * a);
  float t = (1.f - e) / (1.f + e);
  return copysignf(t, x);
}

__device__ __forceinline__ void gload_lds16(const void* g, void* l) {
  __builtin_amdgcn_global_load_lds(
      (const __attribute__((address_space(1))) unsigned int*)g,
      (__attribute__((address_space(3))) unsigned int*)l, 16, 0, 0);
}

// --- per-instruction device-coherent (IC-level) accessors ---
__device__ __forceinline__ unsigned ld_flag_sc(const unsigned* p) {
  unsigned r;
  asm volatile("global_load_dword %0, %1, off sc0 sc1\n\ts_waitcnt vmcnt(0)"
               : "=v"(r) : "v"(p) : "memory");
  return r;
}
__device__ __forceinline__ void st16b_sc(u16* p, unsigned v) {
  asm volatile("global_store_short %0, %1, off sc0 sc1" :: "v"(p), "v"(v) : "memory");
}
__device__ __forceinline__ void st32b_sc(unsigned* p, unsigned v) {
  asm volatile("global_store_dword %0, %1, off sc0 sc1" :: "v"(p), "v"(v) : "memory");
}

// X [32,4,1024,128] f32 -> st[n=b*1024+t][hi(512)|lo(512)] bf16
__global__ void k_gather_x(const float* __restrict__ X, u16* __restrict__ st) {
  int64_t i = (int64_t)blockIdx.x * 256 + threadIdx.x;  // 16,777,216
  int k = (int)(i & 511);
  int t = (int)((i >> 9) & 1023);
  int b = (int)(i >> 19);
  int c = k >> 7, f = k & 127;
  float v = X[(((int64_t)(b * 4 + c) * 1024 + t) << 7) + f];
  u16 hi = f2bf(v);
  u16 lo = f2bf(v - bf2f(hi));
  int64_t n = (int64_t)b * 1024 + t;
  st[n * KS + k] = hi;
  st[n * KS + 512 + k] = lo;
}

// W [2048,512] f32 -> Wp[2048][hi(512)|lo(512)] bf16
__global__ void k_split_w(const float* __restrict__ W, u16* __restrict__ Wp) {
  int i = blockIdx.x * 256 + threadIdx.x;  // 1,048,576
  int r = i >> 9, k = i & 511;
  float v = W[i];
  u16 hi = f2bf(v);
  u16 lo = f2bf(v - bf2f(hi));
  Wp[r * KS + k] = hi;
  Wp[r * KS + 512 + k] = lo;
}

__global__ void k_bias(const float* __restrict__ bi, const float* __restrict__ bh,
                       float* __restrict__ bo) {
  int i = blockIdx.x * 256 + threadIdx.x;
  if (i < N4H) bo[i] = bi[i] + bh[i];
}

// G[b*CT+dt][2048] = st[b*1024+t0+dt][:] * Wp^T + bias   (split-bf16, K'=1536)
// 128x128 tile, BK=64, 4 waves 2x2, global_load_lds staging (m97 structure).
__launch_bounds__(256, 2)
__global__ void k_xproj(const u16* __restrict__ A, const u16* __restrict__ Wp,
                        const float* __restrict__ bias, float* __restrict__ G,
                        int t0) {
  __shared__ u16 As[128 * 64];
  __shared__ u16 Bs[128 * 64];
  const int tid = threadIdx.x;
  const int lane = tid & 63;
  const int wv = tid >> 6;
  const int wm = wv & 1, wn = wv >> 1;
  const int ntile = blockIdx.x & 15;
  const int mtile = blockIdx.x >> 4;          // 0..63
  const int b = mtile >> 1;
  const int dt0 = (mtile & 1) << 7;
  const int64_t arow0 = (int64_t)b * NT + t0 + dt0;   // global st row
  const int grow0 = mtile * 128;                      // G chunk row
  const int brow0 = ntile * 128;

  f32x4 acc[4][4];
#pragma unroll
  for (int m = 0; m < 4; ++m)
#pragma unroll
    for (int n = 0; n < 4; ++n) acc[m][n] = (f32x4){0.f, 0.f, 0.f, 0.f};

  const int srow = tid >> 3;       // 0..31
  const int scol = (tid & 7) * 8;  // elements; *2B = lane-linear 16B LDS dma

  for (int kt = 0; kt < 24; ++kt) {
    const int r = kt >> 3;
    const int abase = ((r == 2) ? 512 : 0) + ((kt & 7) << 6);  // A: hi,hi,lo
    const int bbase = ((r == 1) ? 512 : 0) + ((kt & 7) << 6);  // B: hi,lo,hi
#pragma unroll
    for (int i = 0; i < 4; ++i) {
      int row = srow + i * 32;
      int e = row * 64 + scol;
      gload_lds16(A + (arow0 + row) * KS + abase + scol, As + e);
      gload_lds16(Wp + (int64_t)(brow0 + row) * KS + bbase + scol, Bs + e);
    }
    __syncthreads();
#pragma unroll
    for (int kk = 0; kk < 2; ++kk) {
      const int krow = kk * 32 + (lane >> 4) * 8;
      short8 af[4], bf[4];
#pragma unroll
      for (int m = 0; m < 4; ++m)
        af[m] = *(const short8*)&As[(wm * 64 + m * 16 + (lane & 15)) * 64 + krow];
#pragma unroll
      for (int n = 0; n < 4; ++n)
        bf[n] = *(const short8*)&Bs[(wn * 64 + n * 16 + (lane & 15)) * 64 + krow];
#pragma unroll
      for (int m = 0; m < 4; ++m)
#pragma unroll
        for (int n = 0; n < 4; ++n)
          acc[m][n] = __builtin_amdgcn_mfma_f32_16x16x32_bf16(af[m], bf[n], acc[m][n], 0, 0, 0);
    }
    __syncthreads();
  }

  // C/D: col = lane&15, row = (lane>>4)*4 + j  [m89-verified]
  const int cb = lane & 15;
  const int rb = (lane >> 4) * 4;
#pragma unroll
  for (int m = 0; m < 4; ++m) {
#pragma unroll
    for (int n = 0; n < 4; ++n) {
      const int grow = grow0 + wm * 64 + m * 16 + rb;
      const int gcol = brow0 + wn * 64 + n * 16 + cb;
      const float bv = bias[gcol];
#pragma unroll
      for (int j = 0; j < 4; ++j)
        G[(int64_t)(grow + j) * N4H + gcol] = acc[m][n][j] + bv;
    }
  }
}

// ---------------------------------------------------------------------------
// Recurrent chunk, register-resident W_hh, MFMA, sc1 flag barrier (round-4
// structure). 64 WGs x 256 thr. WG ug owns units ug*8..ug*8+7 (x4 gates = 32
// rows), all 32 batches. Wave wv: mt=wv&1 (unit-half), nt=wv>>1 (batch-half).
// Lane's acc j-components = gates i,f,g,o of unit (ug*8 + mt*4 + q),
// batch (nt*16 + cb).  K'=1536 regions: A=[Whi|Whi|Wlo], B=[hhi|hlo|hhi].
// h-loads: ONE agent-acquire (buffer_inv) per step, then PLAIN cached loads.
// ---------------------------------------------------------------------------
__launch_bounds__(256, 1)
__global__ void k_lstm(const float* __restrict__ Whh, const float* __restrict__ G,
                       u16* __restrict__ st, float* __restrict__ cbuf,
                       unsigned* __restrict__ flags, int t0, unsigned base) {
  const int tid = threadIdx.x;
  const int lane = tid & 63;
  const int wv = tid >> 6;
  const int mt = wv & 1, nt = wv >> 1;
  const int ug = blockIdx.x;      // 0..63
  const int q = lane >> 4;        // 0..3
  const int cb = lane & 15;

  // --- stage this lane's 32 W_hh frags (split bf16) into registers ---
  short8 whi[16], wlo[16];
  {
    const int tr = lane & 15;                 // A-row within tile
    const int gate = tr & 3;
    const int u_row = mt * 4 + (tr >> 2);
    const int64_t R = (int64_t)gate * 512 + ug * 8 + u_row;
    const float* wsrc = Whh + R * 512 + q * 8;
#pragma unroll
    for (int kk = 0; kk < 16; ++kk) {
      float4 a = *(const float4*)(wsrc + kk * 32);
      float4 b = *(const float4*)(wsrc + kk * 32 + 4);
      float v[8] = {a.x, a.y, a.z, a.w, b.x, b.y, b.z, b.w};
      ushort8 hi8, lo8;
#pragma unroll
      for (int e = 0; e < 8; ++e) {
        u16 h = f2bf(v[e]);
        hi8[e] = h;
        lo8[e] = f2bf(v[e] - bf2f(h));
      }
      whi[kk] = (short8)hi8;
      wlo[kk] = (short8)lo8;
    }
  }

  const int bat = nt * 16 + cb;
  const int ucol = ug * 8 + mt * 4 + q;
  float cst = (t0 > 0) ? cbuf[bat * NH + ucol] : 0.f;

  for (int s = 0; s < CT; ++s) {
    const int ts = t0 + s;

    // G loads: plain cached reads, independent of the barrier -> issue first
    const float* gp = G + ((int64_t)bat * CT + s) * N4H + ucol;
    float g0 = gp[0], g1 = gp[512], g2 = gp[1024], g3 = gp[1536];

    f32x4 acc0 = {0.f, 0.f, 0.f, 0.f};
    f32x4 acc1 = {0.f, 0.f, 0.f, 0.f};
    f32x4 acc2 = {0.f, 0.f, 0.f, 0.f};

    if (ts > 0) {
      if (s > 0) {  // wait for all 64 WGs to have published h(ts-1)
        const unsigned tgt = base + (unsigned)s;
        int gd = 0;
        for (;;) {
          unsigned f = ld_flag_sc(flags + lane);
          if (__all((int)(f >= tgt))) break;
          __builtin_amdgcn_s_sleep(1);
          if (++gd > (1 << 18)) break;  // anomaly: fail fast to wrong output
        }
      }
      // One agent-scope acquire -> buffer_inv sc1 (clean L1+L2 invalidate):
      // the h lines published via sc0sc1 stores are then safely readable
      // through the caches. Redundant reads (2 waves/WG, ~32 WGs/XCD) hit L2.
      __hip_atomic_load(flags + ug, __ATOMIC_ACQUIRE, __HIP_MEMORY_SCOPE_AGENT);

      const u16* hb = st + ((int64_t)bat * NT + (ts - 1)) * KS + q * 8;
      uint4 hh[16], hl[16];
#pragma unroll
      for (int kk = 0; kk < 16; ++kk) {
        hh[kk] = *(const uint4*)(hb + kk * 32);        // hi plane (cached)
        hl[kk] = *(const uint4*)(hb + 512 + kk * 32);  // lo plane (cached)
      }
#pragma unroll
      for (int kk = 0; kk < 16; ++kk) {
        short8 hhv = __builtin_bit_cast(short8, hh[kk]);
        short8 hlv = __builtin_bit_cast(short8, hl[kk]);
        acc0 = __builtin_amdgcn_mfma_f32_16x16x32_bf16(whi[kk], hhv, acc0, 0, 0, 0);
        acc1 = __builtin_amdgcn_mfma_f32_16x16x32_bf16(whi[kk], hlv, acc1, 0, 0, 0);
        acc2 = __builtin_amdgcn_mfma_f32_16x16x32_bf16(wlo[kk], hhv, acc2, 0, 0, 0);
      }
    }

    float ip = (acc0[0] + acc1[0] + acc2[0]) + g0;
    float fp = (acc0[1] + acc1[1] + acc2[1]) + g1;
    float gg = (acc0[2] + acc1[2] + acc2[2]) + g2;
    float op = (acc0[3] + acc1[3] + acc2[3]) + g3;
    float i_s = sigm(ip), f_s = sigm(fp), g_t = tanh_s(gg), o_s = sigm(op);
    cst = f_s * cst + i_s * g_t;
    float h = o_s * tanh_s(cst);

    u16 hhi = f2bf(h);
    u16 hlo = f2bf(h - bf2f(hhi));
    u16* hp = st + ((int64_t)bat * NT + ts) * KS + ucol;
    st16b_sc(hp, (unsigned)hhi);
    st16b_sc(hp + 512, (unsigned)hlo);
    asm volatile("s_waitcnt vmcnt(0)" ::: "memory");  // h at IC (device-visible)
    __syncthreads();                                   // all 4 waves done
    if (tid == 0)
      st32b_sc(flags + ug, base + (unsigned)s + 1);
  }

  cbuf[bat * NH + ucol] = cst;
}

// out[32,80] = (hi+lo of st[:,1023,:]) @ W_out^T + b_out
__global__ void k_final(const u16* __restrict__ st, const float* __restrict__ Wout,
                        const float* __restrict__ bout, float* __restrict__ out) {
  const int b = blockIdx.x;
  const int o = threadIdx.x;
  if (o >= 80) return;
  const u16* hp = st + ((int64_t)b * NT + (NT - 1)) * KS;
  float acc = bout[o];
  for (int k = 0; k < 512; ++k)
    acc += (bf2f(hp[k]) + bf2f(hp[512 + k])) * Wout[o * 512 + k];
  out[b * 80 + o] = acc;
}

extern "C" void kernel_launch(void* const* d_in, const int* in_sizes, int n_in,
                              void* d_out, int out_size, void* d_ws, size_t ws_size,
                              hipStream_t stream) {
  const float* X = (const float*)d_in[0];
  const float* Wih[3] = {(const float*)d_in[1], (const float*)d_in[5], (const float*)d_in[9]};
  const float* Whh[3] = {(const float*)d_in[2], (const float*)d_in[6], (const float*)d_in[10]};
  const float* bih[3] = {(const float*)d_in[3], (const float*)d_in[7], (const float*)d_in[11]};
  const float* bhh[3] = {(const float*)d_in[4], (const float*)d_in[8], (const float*)d_in[12]};
  const float* Wout = (const float*)d_in[13];
  const float* bout = (const float*)d_in[14];
  float* out = (float*)d_out;

  char* ws = (char*)d_ws;
  size_t off = 0;
  auto alloc = [&](size_t bytes) {
    char* p = ws + off;
    off = (off + bytes + 255) & ~(size_t)255;
    return p;
  };
  u16* st = (u16*)alloc((size_t)MROWS * KS * 2);          // 64 MiB
  float* G = (float*)alloc((size_t)NB * CT * N4H * 4);    // 64 MiB
  u16* Wp[3];
  for (int l = 0; l < 3; ++l) Wp[l] = (u16*)alloc((size_t)N4H * KS * 2);  // 4 MiB each
  float* bias[3];
  for (int l = 0; l < 3; ++l) bias[l] = (float*)alloc(N4H * 4);
  float* cbuf = (float*)alloc(NB * NH * 4);               // 64 KiB
  unsigned* flags = (unsigned*)alloc(64 * 4);
  // total ~140.4 MiB

  hipMemsetAsync(flags, 0, 64 * 4, stream);
  k_gather_x<<<65536, 256, 0, stream>>>(X, st);
  for (int l = 0; l < 3; ++l) {
    k_split_w<<<4096, 256, 0, stream>>>(Wih[l], Wp[l]);
    k_bias<<<8, 256, 0, stream>>>(bih[l], bhh[l], bias[l]);
  }

  for (int l = 0; l < 3; ++l) {
    for (int c = 0; c < NT / CT; ++c) {
      const int t0 = c * CT;
      const unsigned base = (unsigned)(l * 4 + c) * CT;
      k_xproj<<<1024, 256, 0, stream>>>(st, Wp[l], bias[l], G, t0);
      k_lstm<<<64, 256, 0, stream>>>(Whh[l], G, st, cbuf, flags, t0, base);
    }
  }

  k_final<<<32, 128, 0, stream>>>(st, Wout, bout, out);
}

// Round 12
// 12901.286 us; speedup vs baseline: 3.0730x; 1.9014x over previous
//
#include <hip/hip_runtime.h>
#include <cstdint>

// ---------------------------------------------------------------------------
// 3-layer LSTM (B=32, T=1024, H=I=512), PyTorch gate order (i,f,g,o).
// WAVEFRONT-PIPELINED recurrence (round-9 structure, round-10 fixes the
// W_ih LDS indexing bug: read stride/plane now match the staged layout).
// ROUND 12 = round 10 resubmitted verbatim (container died before testing,
// rounds 10 and 11 -- same pod, connection closed at first message).
//  - Critical path 3072 -> ~1026 steps: 3 layers run concurrently;
//    layer l at time t needs only (l-1,t) and (l,t-1).
//  - k_lstm3: 192 WGs x 256 thr = 3 layers x (r4-verified 64-WG structure).
//    Layer 0 reads G (X-projection GEMM, chunked). Layers 1,2 compute their
//    input projection IN-KERNEL: W_ih split-bf16 in XOR-swizzled LDS
//    ([row 0..31] stride 1024 u16, planes +0/+512), W_hh in registers.
//  - h exchange: hring[3][16] ring (3MB), sc0sc1 stores/loads (r4-proven);
//    flags = absolute timestep per (layer,WG); downstream throttle every
//    8 steps guards ring WAR (writer step x+16 requires fl_dn >= x+1,
//    throttle provides >= x+1..x+8).
//  - 192 WGs <= 256 CUs: co-resident by construction, placement-independent.
//  - Numerics: identical split-bf16 3-term MFMA everywhere (verified 3.8e-6).
// ---------------------------------------------------------------------------

typedef unsigned short u16;
typedef short short8 __attribute__((ext_vector_type(8)));
typedef unsigned short ushort8 __attribute__((ext_vector_type(8)));
typedef float f32x4 __attribute__((ext_vector_type(4)));

#define NB 32
#define NT 1024
#define NH 512
#define N4H 2048
#define KS 1024   // stored row: [hi(512) | lo(512)] bf16
#define CT 256    // time chunk (G buffer granularity)
#define RR 16     // hring depth (power of 2)
#define MROWS (NB * NT)

__device__ __forceinline__ u16 f2bf(float f) {
  uint32_t u = __float_as_uint(f);
  uint32_t r = (u + 0x7fffu + ((u >> 16) & 1u)) >> 16;
  return (u16)r;
}
__device__ __forceinline__ float bf2f(u16 h) {
  return __uint_as_float((uint32_t)h << 16);
}
__device__ __forceinline__ float sigm(float x) { return 1.f / (1.f + __expf(-x)); }
__device__ __forceinline__ float tanh_s(float x) {
  float a = fabsf(x);
  float e = __expf(-2.f * a);
  float t = (1.f - e) / (1.f + e);
  return copysignf(t, x);
}

__device__ __forceinline__ void gload_lds16(const void* g, void* l) {
  __builtin_amdgcn_global_load_lds(
      (const __attribute__((address_space(1))) unsigned int*)g,
      (__attribute__((address_space(3))) unsigned int*)l, 16, 0, 0);
}

// --- per-instruction device-coherent (IC-level) accessors ---
__device__ __forceinline__ void ld16_sc(const u16* p, uint4& d) {
  asm volatile("global_load_dwordx4 %0, %1, off sc0 sc1" : "=v"(d) : "v"(p));
}
__device__ __forceinline__ int ldf(const int* p) {
  int r;
  asm volatile("global_load_dword %0, %1, off sc0 sc1\n\ts_waitcnt vmcnt(0)"
               : "=v"(r) : "v"(p) : "memory");
  return r;
}
__device__ __forceinline__ void st16b_sc(u16* p, unsigned v) {
  asm volatile("global_store_short %0, %1, off sc0 sc1" :: "v"(p), "v"(v) : "memory");
}
__device__ __forceinline__ void st32b_sc(int* p, int v) {
  asm volatile("global_store_dword %0, %1, off sc0 sc1" :: "v"(p), "v"(v) : "memory");
}

// X [32,4,1024,128] f32 -> xs[n=b*1024+t][hi(512)|lo(512)] bf16
__global__ void k_gather_x(const float* __restrict__ X, u16* __restrict__ xs) {
  int64_t i = (int64_t)blockIdx.x * 256 + threadIdx.x;  // 16,777,216
  int k = (int)(i & 511);
  int t = (int)((i >> 9) & 1023);
  int b = (int)(i >> 19);
  int c = k >> 7, f = k & 127;
  float v = X[(((int64_t)(b * 4 + c) * 1024 + t) << 7) + f];
  u16 hi = f2bf(v);
  u16 lo = f2bf(v - bf2f(hi));
  int64_t n = (int64_t)b * 1024 + t;
  xs[n * KS + k] = hi;
  xs[n * KS + 512 + k] = lo;
}

// W [2048,512] f32 -> Wp[2048][hi(512)|lo(512)] bf16
__global__ void k_split_w(const float* __restrict__ W, u16* __restrict__ Wp) {
  int i = blockIdx.x * 256 + threadIdx.x;  // 1,048,576
  int r = i >> 9, k = i & 511;
  float v = W[i];
  u16 hi = f2bf(v);
  u16 lo = f2bf(v - bf2f(hi));
  Wp[r * KS + k] = hi;
  Wp[r * KS + 512 + k] = lo;
}

__global__ void k_bias(const float* __restrict__ bi, const float* __restrict__ bh,
                       float* __restrict__ bo) {
  int i = blockIdx.x * 256 + threadIdx.x;
  if (i < N4H) bo[i] = bi[i] + bh[i];
}

// G[b*CT+dt][2048] = xs[b*1024+t0+dt][:] * Wp0^T + bias0   (split-bf16 K'=1536)
__launch_bounds__(256, 2)
__global__ void k_xproj(const u16* __restrict__ A, const u16* __restrict__ Wp,
                        const float* __restrict__ bias, float* __restrict__ G,
                        int t0) {
  __shared__ u16 As[128 * 64];
  __shared__ u16 Bs[128 * 64];
  const int tid = threadIdx.x;
  const int lane = tid & 63;
  const int wv = tid >> 6;
  const int wm = wv & 1, wn = wv >> 1;
  const int ntile = blockIdx.x & 15;
  const int mtile = blockIdx.x >> 4;          // 0..63
  const int b = mtile >> 1;
  const int dt0 = (mtile & 1) << 7;
  const int64_t arow0 = (int64_t)b * NT + t0 + dt0;
  const int grow0 = mtile * 128;
  const int brow0 = ntile * 128;

  f32x4 acc[4][4];
#pragma unroll
  for (int m = 0; m < 4; ++m)
#pragma unroll
    for (int n = 0; n < 4; ++n) acc[m][n] = (f32x4){0.f, 0.f, 0.f, 0.f};

  const int srow = tid >> 3;
  const int scol = (tid & 7) * 8;

  for (int kt = 0; kt < 24; ++kt) {
    const int r = kt >> 3;
    const int abase = ((r == 2) ? 512 : 0) + ((kt & 7) << 6);  // A: hi,hi,lo
    const int bbase = ((r == 1) ? 512 : 0) + ((kt & 7) << 6);  // B: hi,lo,hi
#pragma unroll
    for (int i = 0; i < 4; ++i) {
      int row = srow + i * 32;
      int e = row * 64 + scol;
      gload_lds16(A + (arow0 + row) * KS + abase + scol, As + e);
      gload_lds16(Wp + (int64_t)(brow0 + row) * KS + bbase + scol, Bs + e);
    }
    __syncthreads();
#pragma unroll
    for (int kk = 0; kk < 2; ++kk) {
      const int krow = kk * 32 + (lane >> 4) * 8;
      short8 af[4], bf[4];
#pragma unroll
      for (int m = 0; m < 4; ++m)
        af[m] = *(const short8*)&As[(wm * 64 + m * 16 + (lane & 15)) * 64 + krow];
#pragma unroll
      for (int n = 0; n < 4; ++n)
        bf[n] = *(const short8*)&Bs[(wn * 64 + n * 16 + (lane & 15)) * 64 + krow];
#pragma unroll
      for (int m = 0; m < 4; ++m)
#pragma unroll
        for (int n = 0; n < 4; ++n)
          acc[m][n] = __builtin_amdgcn_mfma_f32_16x16x32_bf16(af[m], bf[n], acc[m][n], 0, 0, 0);
    }
    __syncthreads();
  }

  const int cb = lane & 15;
  const int rb = (lane >> 4) * 4;
#pragma unroll
  for (int m = 0; m < 4; ++m) {
#pragma unroll
    for (int n = 0; n < 4; ++n) {
      const int grow = grow0 + wm * 64 + m * 16 + rb;
      const int gcol = brow0 + wn * 64 + n * 16 + cb;
      const float bv = bias[gcol];
#pragma unroll
      for (int j = 0; j < 4; ++j)
        G[(int64_t)(grow + j) * N4H + gcol] = acc[m][n][j] + bv;
    }
  }
}

// ---------------------------------------------------------------------------
// Pipelined 3-layer recurrent chunk. 192 WGs x 256 thr: l=wg>>6, ug=wg&63.
// Per layer: r4 partition (wave mt/nt; lane q,cb; bat=nt*16+cb,
// ucol=ug*8+mt*4+q; A-row tr=lane&15 -> gate=tr&3, u_row=mt*4+tr>>2).
// Step ts for layer l: gates = [l==0: G] or [W_ih(LDS)*h_{l-1,ts} + bias] +
// W_hh(regs)*h_{l,ts-1}; h published to hring[l][ts&15] (sc0sc1) + flag=ts+1.
// W_ih LDS layout: row r=mt*16+tr at r*1024 u16, hi plane +0, lo plane +512,
// elements XOR-swizzled by ((tr&7)<<3).
// ---------------------------------------------------------------------------
__launch_bounds__(256, 1)
__global__ void k_lstm3(const float* __restrict__ Whh0, const float* __restrict__ Whh1,
                        const float* __restrict__ Whh2,
                        const u16* __restrict__ Wp1, const u16* __restrict__ Wp2,
                        const float* __restrict__ bias1, const float* __restrict__ bias2,
                        const float* __restrict__ G, u16* __restrict__ hring,
                        float* __restrict__ cbuf, u16* __restrict__ hfinal,
                        int* __restrict__ flags, int t0) {
  __shared__ u16 wlds[32768];  // W_ih split (l>0), 64 KB
  const int tid = threadIdx.x;
  const int lane = tid & 63;
  const int wv = tid >> 6;
  const int mt = wv & 1, nt = wv >> 1;
  const int wg = blockIdx.x;
  const int l = wg >> 6;
  const int ug = wg & 63;
  const int q = lane >> 4;
  const int cb = lane & 15;
  const int tr = lane & 15;

  const float* Whh = (l == 0) ? Whh0 : (l == 1) ? Whh1 : Whh2;

  // --- W_hh frags (split bf16) into registers [r4-verified] ---
  short8 whi[16], wlo[16];
  {
    const int gate = tr & 3;
    const int u_row = mt * 4 + (tr >> 2);
    const int64_t R = (int64_t)gate * 512 + ug * 8 + u_row;
    const float* wsrc = Whh + R * 512 + q * 8;
#pragma unroll
    for (int kk = 0; kk < 16; ++kk) {
      float4 a = *(const float4*)(wsrc + kk * 32);
      float4 b = *(const float4*)(wsrc + kk * 32 + 4);
      float v[8] = {a.x, a.y, a.z, a.w, b.x, b.y, b.z, b.w};
      ushort8 hi8, lo8;
#pragma unroll
      for (int e = 0; e < 8; ++e) {
        u16 h = f2bf(v[e]);
        hi8[e] = h;
        lo8[e] = f2bf(v[e] - bf2f(h));
      }
      whi[kk] = (short8)hi8;
      wlo[kk] = (short8)lo8;
    }
  }

  // --- W_ih (l>0) from Wp into LDS: row r at r*1024, planes +0/+512, XOR-swz
  if (l > 0) {
    const u16* Wp = (l == 1) ? Wp1 : Wp2;
#pragma unroll
    for (int i = 0; i < 16; ++i) {
      int id = tid + i * 256;        // 4096 chunks of 8 u16
      int r = id >> 7;               // 0..31 = mt*16 + tr2
      int p = (id >> 6) & 1;
      int kc = (id & 63) * 8;
      int tr2 = r & 15;
      int grow = (tr2 & 3) * 512 + ug * 8 + ((r >> 4) * 4 + (tr2 >> 2));
      ushort8 v = *(const ushort8*)(Wp + (int64_t)grow * KS + p * 512 + kc);
      *(ushort8*)&wlds[((r * 2 + p) << 9) + (kc ^ ((tr2 & 7) << 3))] = v;
    }
  }
  __syncthreads();

  const int bat = nt * 16 + cb;
  const int ucol = ug * 8 + mt * 4 + q;
  float b0 = 0.f, b1 = 0.f, b2 = 0.f, b3 = 0.f;
  if (l > 0) {
    const float* bs = (l == 1) ? bias1 : bias2;
    b0 = bs[ucol]; b1 = bs[512 + ucol]; b2 = bs[1024 + ucol]; b3 = bs[1536 + ucol];
  }
  float cst = (t0 > 0) ? cbuf[(l * NB + bat) * NH + ucol] : 0.f;

  int* fl_own = flags + l * 64;
  int* fl_up = flags + (l - 1) * 64;
  int* fl_dn = flags + (l + 1) * 64;
  const int wibase = (mt * 16 + tr) * 1024;  // u16 idx of this lane's W_ih row
  const int wswz = (tr & 7) << 3;

  for (int s = 0; s < CT; ++s) {
    const int ts = t0 + s;

    float g0, g1, g2, g3;
    if (l == 0) {  // G prefetch (cached), independent of barrier
      const float* gp = G + ((int64_t)bat * CT + s) * N4H + ucol;
      g0 = gp[0]; g1 = gp[512]; g2 = gp[1024]; g3 = gp[1536];
    } else {
      g0 = b0; g1 = b1; g2 = b2; g3 = b3;
    }

    // --- combined poll: own(ts) / upstream(ts+1) / throttle(ts-8 every 8) ---
    {
      const bool chk_own = (ts > 0);
      const bool chk_up = (l > 0);
      const bool chk_dn = (l < 2) && ((ts & 7) == 0);
      if (chk_own | chk_up | chk_dn) {
        int gd = 0;
        for (;;) {
          int ok = 1;
          if (chk_own) ok &= (ldf(fl_own + lane) >= ts);
          if (chk_up) ok &= (ldf(fl_up + lane) >= ts + 1);
          if (chk_dn) ok &= (ldf(fl_dn + lane) >= ts - 8);
          if (__all(ok)) break;
          __builtin_amdgcn_s_sleep(2);
          if (++gd > (1 << 12)) break;  // anomaly: fail fast to wrong output
        }
      }
    }

    f32x4 acc0 = {0.f, 0.f, 0.f, 0.f};
    f32x4 acc1 = {0.f, 0.f, 0.f, 0.f};
    f32x4 acc2 = {0.f, 0.f, 0.f, 0.f};
    uint4 hh[16], hl[16];

    // Phase 1: recurrent term W_hh * h_{l,ts-1}
    if (ts > 0) {
      const u16* hr = hring + (((l * RR + ((ts - 1) & (RR - 1))) * NB + bat) << 10) + q * 8;
#pragma unroll
      for (int kk = 0; kk < 16; ++kk) {
        ld16_sc(hr + kk * 32, hh[kk]);
        ld16_sc(hr + 512 + kk * 32, hl[kk]);
      }
      asm volatile("s_waitcnt vmcnt(0)" ::: "memory");
      __builtin_amdgcn_sched_barrier(0);
#pragma unroll
      for (int kk = 0; kk < 16; ++kk) {
        short8 hhv = __builtin_bit_cast(short8, hh[kk]);
        short8 hlv = __builtin_bit_cast(short8, hl[kk]);
        acc0 = __builtin_amdgcn_mfma_f32_16x16x32_bf16(whi[kk], hhv, acc0, 0, 0, 0);
        acc1 = __builtin_amdgcn_mfma_f32_16x16x32_bf16(whi[kk], hlv, acc1, 0, 0, 0);
        acc2 = __builtin_amdgcn_mfma_f32_16x16x32_bf16(wlo[kk], hhv, acc2, 0, 0, 0);
      }
      __builtin_amdgcn_sched_barrier(0);
    }

    // Phase 2 (l>0): input term W_ih * h_{l-1,ts} (W frags from swizzled LDS)
    if (l > 0) {
      const u16* xr = hring + ((((l - 1) * RR + (ts & (RR - 1))) * NB + bat) << 10) + q * 8;
#pragma unroll
      for (int kk = 0; kk < 16; ++kk) {
        ld16_sc(xr + kk * 32, hh[kk]);
        ld16_sc(xr + 512 + kk * 32, hl[kk]);
      }
      asm volatile("s_waitcnt vmcnt(0)" ::: "memory");
      __builtin_amdgcn_sched_barrier(0);
#pragma unroll
      for (int kk = 0; kk < 16; ++kk) {
        const int kidx = (kk * 32 + q * 8) ^ wswz;
        short8 wih = *(const short8*)&wlds[wibase + kidx];         // hi plane
        short8 wil = *(const short8*)&wlds[wibase + 512 + kidx];   // lo plane
        short8 xhv = __builtin_bit_cast(short8, hh[kk]);
        short8 xlv = __builtin_bit_cast(short8, hl[kk]);
        acc0 = __builtin_amdgcn_mfma_f32_16x16x32_bf16(wih, xhv, acc0, 0, 0, 0);
        acc1 = __builtin_amdgcn_mfma_f32_16x16x32_bf16(wih, xlv, acc1, 0, 0, 0);
        acc2 = __builtin_amdgcn_mfma_f32_16x16x32_bf16(wil, xhv, acc2, 0, 0, 0);
      }
    }

    float ip = (acc0[0] + acc1[0] + acc2[0]) + g0;
    float fp = (acc0[1] + acc1[1] + acc2[1]) + g1;
    float gg = (acc0[2] + acc1[2] + acc2[2]) + g2;
    float op = (acc0[3] + acc1[3] + acc2[3]) + g3;
    float i_s = sigm(ip), f_s = sigm(fp), g_t = tanh_s(gg), o_s = sigm(op);
    cst = f_s * cst + i_s * g_t;
    float h = o_s * tanh_s(cst);

    u16 hhi = f2bf(h);
    u16 hlo = f2bf(h - bf2f(hhi));
    u16* hw = hring + (((l * RR + (ts & (RR - 1))) * NB + bat) << 10) + ucol;
    st16b_sc(hw, (unsigned)hhi);
    st16b_sc(hw + 512, (unsigned)hlo);
    if (l == 2 && ts == NT - 1) {
      hfinal[bat * 1024 + ucol] = hhi;
      hfinal[bat * 1024 + 512 + ucol] = hlo;
    }
    asm volatile("s_waitcnt vmcnt(0)" ::: "memory");  // h at IC
    __syncthreads();                                   // all 4 waves done
    if (tid == 0) st32b_sc(fl_own + ug, ts + 1);
  }

  cbuf[(l * NB + bat) * NH + ucol] = cst;
}

// out[32,80] = (hi+lo of hfinal) @ W_out^T + b_out
__global__ void k_final(const u16* __restrict__ hfinal, const float* __restrict__ Wout,
                        const float* __restrict__ bout, float* __restrict__ out) {
  const int b = blockIdx.x;
  const int o = threadIdx.x;
  if (o >= 80) return;
  const u16* hp = hfinal + b * 1024;
  float acc = bout[o];
  for (int k = 0; k < 512; ++k)
    acc += (bf2f(hp[k]) + bf2f(hp[512 + k])) * Wout[o * 512 + k];
  out[b * 80 + o] = acc;
}

extern "C" void kernel_launch(void* const* d_in, const int* in_sizes, int n_in,
                              void* d_out, int out_size, void* d_ws, size_t ws_size,
                              hipStream_t stream) {
  const float* X = (const float*)d_in[0];
  const float* Wih[3] = {(const float*)d_in[1], (const float*)d_in[5], (const float*)d_in[9]};
  const float* Whh[3] = {(const float*)d_in[2], (const float*)d_in[6], (const float*)d_in[10]};
  const float* bih[3] = {(const float*)d_in[3], (const float*)d_in[7], (const float*)d_in[11]};
  const float* bhh[3] = {(const float*)d_in[4], (const float*)d_in[8], (const float*)d_in[12]};
  const float* Wout = (const float*)d_in[13];
  const float* bout = (const float*)d_in[14];
  float* out = (float*)d_out;

  char* ws = (char*)d_ws;
  size_t off = 0;
  auto alloc = [&](size_t bytes) {
    char* p = ws + off;
    off = (off + bytes + 255) & ~(size_t)255;
    return p;
  };
  u16* xs = (u16*)alloc((size_t)MROWS * KS * 2);          // 64 MiB
  float* G = (float*)alloc((size_t)NB * CT * N4H * 4);    // 64 MiB
  u16* Wp[3];
  for (int l = 0; l < 3; ++l) Wp[l] = (u16*)alloc((size_t)N4H * KS * 2);  // 4 MiB each
  float* bias[3];
  for (int l = 0; l < 3; ++l) bias[l] = (float*)alloc(N4H * 4);
  float* cbuf = (float*)alloc(3 * NB * NH * 4);           // 192 KiB
  u16* hring = (u16*)alloc((size_t)3 * RR * NB * KS * 2); // 3 MiB
  u16* hfinal = (u16*)alloc(NB * 1024 * 2);               // 64 KiB
  int* flags = (int*)alloc(3 * 64 * 4);                   // 768 B
  // total ~143.5 MiB

  hipMemsetAsync(flags, 0, 3 * 64 * 4, stream);
  k_gather_x<<<65536, 256, 0, stream>>>(X, xs);
  for (int l = 0; l < 3; ++l) {
    k_split_w<<<4096, 256, 0, stream>>>(Wih[l], Wp[l]);
    k_bias<<<8, 256, 0, stream>>>(bih[l], bhh[l], bias[l]);
  }

  for (int c = 0; c < NT / CT; ++c) {
    const int t0 = c * CT;
    k_xproj<<<1024, 256, 0, stream>>>(xs, Wp[0], bias[0], G, t0);
    k_lstm3<<<192, 256, 0, stream>>>(Whh[0], Whh[1], Whh[2], Wp[1], Wp[2],
                                     bias[1], bias[2], G, hring, cbuf, hfinal,
                                     flags, t0);
  }

  k_final<<<32, 128, 0, stream>>>(hfinal, Wout, bout, out);
}

// Round 13
// 8646.944 us; speedup vs baseline: 4.5850x; 1.4920x over previous
//
#include <hip/hip_runtime.h>
#include <cstdint>

// ---------------------------------------------------------------------------
// 3-layer LSTM (B=32, T=1024, H=I=512), PyTorch gate order (i,f,g,o).
// ROUND 13: fully-unified single-launch wavefront pipeline + LDS staging.
// r12 model fit: step = 1.4us + 2.7ns x (64B lines/CU). r12 paid 4096 lines
// (2 direct-load phases, 4 lanes/line, 2x wave redundancy). This round:
//  - Cooperative LDS staging: each 64KB B-operand (own h(ts-1), input(ts))
//    loaded ONCE per CU with dense coalescing (1024 lines/stage), MFMA reads
//    B-frags from LDS (XOR-swizzle by batch, write/read consistent).
//  - Layer 0 unified: W_ih0 * x(ts) computed in-kernel from xs (same row
//    format as hring) -> k_xproj + 64MB G buffer DELETED, balanced pipeline.
//  - ONE k_lstm3 launch for all 1024 steps (no chunk drains; c in regs).
//  - h exchange keeps hi+lo split-bf16 (verified 3.8e-6); flags/throttle
//    protocol identical to r12 (verified).
// Predicted step ~7.2us -> total ~7.6-8ms (from 12.9).
// ---------------------------------------------------------------------------

typedef unsigned short u16;
typedef short short8 __attribute__((ext_vector_type(8)));
typedef unsigned short ushort8 __attribute__((ext_vector_type(8)));
typedef float f32x4 __attribute__((ext_vector_type(4)));

#define NB 32
#define NT 1024
#define NH 512
#define N4H 2048
#define KS 1024   // stored row: [hi(512) | lo(512)] bf16
#define RR 16     // hring depth (power of 2)
#define MROWS (NB * NT)

__device__ __forceinline__ u16 f2bf(float f) {
  uint32_t u = __float_as_uint(f);
  uint32_t r = (u + 0x7fffu + ((u >> 16) & 1u)) >> 16;
  return (u16)r;
}
__device__ __forceinline__ float bf2f(u16 h) {
  return __uint_as_float((uint32_t)h << 16);
}
__device__ __forceinline__ float sigm(float x) { return 1.f / (1.f + __expf(-x)); }
__device__ __forceinline__ float tanh_s(float x) {
  float a = fabsf(x);
  float e = __expf(-2.f * a);
  float t = (1.f - e) / (1.f + e);
  return copysignf(t, x);
}

// --- per-instruction device-coherent (IC-level) accessors ---
__device__ __forceinline__ void ld16_sc(const u16* p, uint4& d) {
  asm volatile("global_load_dwordx4 %0, %1, off sc0 sc1" : "=v"(d) : "v"(p));
}
__device__ __forceinline__ int ldf(const int* p) {
  int r;
  asm volatile("global_load_dword %0, %1, off sc0 sc1\n\ts_waitcnt vmcnt(0)"
               : "=v"(r) : "v"(p) : "memory");
  return r;
}
__device__ __forceinline__ void st16b_sc(u16* p, unsigned v) {
  asm volatile("global_store_short %0, %1, off sc0 sc1" :: "v"(p), "v"(v) : "memory");
}
__device__ __forceinline__ void st32b_sc(int* p, int v) {
  asm volatile("global_store_dword %0, %1, off sc0 sc1" :: "v"(p), "v"(v) : "memory");
}

// X [32,4,1024,128] f32 -> xs[n=b*1024+t][hi(512)|lo(512)] bf16
__global__ void k_gather_x(const float* __restrict__ X, u16* __restrict__ xs) {
  int64_t i = (int64_t)blockIdx.x * 256 + threadIdx.x;  // 16,777,216
  int k = (int)(i & 511);
  int t = (int)((i >> 9) & 1023);
  int b = (int)(i >> 19);
  int c = k >> 7, f = k & 127;
  float v = X[(((int64_t)(b * 4 + c) * 1024 + t) << 7) + f];
  u16 hi = f2bf(v);
  u16 lo = f2bf(v - bf2f(hi));
  int64_t n = (int64_t)b * 1024 + t;
  xs[n * KS + k] = hi;
  xs[n * KS + 512 + k] = lo;
}

// W [2048,512] f32 -> Wp[2048][hi(512)|lo(512)] bf16
__global__ void k_split_w(const float* __restrict__ W, u16* __restrict__ Wp) {
  int i = blockIdx.x * 256 + threadIdx.x;  // 1,048,576
  int r = i >> 9, k = i & 511;
  float v = W[i];
  u16 hi = f2bf(v);
  u16 lo = f2bf(v - bf2f(hi));
  Wp[r * KS + k] = hi;
  Wp[r * KS + 512 + k] = lo;
}

__global__ void k_bias(const float* __restrict__ bi, const float* __restrict__ bh,
                       float* __restrict__ bo) {
  int i = blockIdx.x * 256 + threadIdx.x;
  if (i < N4H) bo[i] = bi[i] + bh[i];
}

// ---------------------------------------------------------------------------
// Single-launch pipelined 3-layer LSTM. 192 WGs x 256 thr: l=wg>>6, ug=wg&63.
// Per layer (r12-verified partition): wave (mt=wv&1, nt=wv>>1); lane
// (q=lane>>4, cb=lane&15); bat=nt*16+cb; ucol=ug*8+mt*4+q; A-row tr=lane&15
// -> gate=tr&3, u_row=mt*4+tr>>2.
// Step ts: gates = bias + W_in(LDS)*input(ts) + W_hh(regs)*h_l(ts-1), where
// input = xs(ts) for l=0, hring[l-1][ts&15] for l>0.
// Both B-operands staged into hbuf (64KB LDS) cooperatively per phase:
//   chunk c = i*256+tid: sb=c>>7 (batch), so=(c&127)*8 (elem16 in [hi|lo] row)
//   dst = sb*1024 + (so&512) + ((so&511) ^ ((sb&7)<<3))   [XOR swz by batch]
// MFMA B-read: hbuf[bat*1024 + plane*512 + ((kk*32+q*8)^((bat&7)<<3))].
// W_in LDS layout (r12-verified): row r=mt*16+tr at r*1024, planes +0/+512,
// elem swizzled by ((tr&7)<<3).
// Flags: absolute ts per (layer,WG); poll own>=ts, up>=ts+1; every 8 steps
// downstream>=ts-8 (ring WAR, RR=16). All r12-verified.
// ---------------------------------------------------------------------------
__launch_bounds__(256, 1)
__global__ void k_lstm3(const float* __restrict__ Whh0, const float* __restrict__ Whh1,
                        const float* __restrict__ Whh2,
                        const u16* __restrict__ Wp0, const u16* __restrict__ Wp1,
                        const u16* __restrict__ Wp2,
                        const float* __restrict__ bias0, const float* __restrict__ bias1,
                        const float* __restrict__ bias2,
                        const u16* __restrict__ xs, u16* __restrict__ hring,
                        u16* __restrict__ hfinal, int* __restrict__ flags) {
  __shared__ u16 wlds[32768];  // W_in split, 64 KB
  __shared__ u16 hbuf[32768];  // staged B operand, 64 KB
  const int tid = threadIdx.x;
  const int lane = tid & 63;
  const int wv = tid >> 6;
  const int mt = wv & 1, nt = wv >> 1;
  const int wg = blockIdx.x;
  const int l = wg >> 6;
  const int ug = wg & 63;
  const int q = lane >> 4;
  const int cb = lane & 15;
  const int tr = lane & 15;

  const float* Whh = (l == 0) ? Whh0 : (l == 1) ? Whh1 : Whh2;
  const u16* Wp = (l == 0) ? Wp0 : (l == 1) ? Wp1 : Wp2;
  const float* bs = (l == 0) ? bias0 : (l == 1) ? bias1 : bias2;

  // --- W_hh frags (split bf16) into registers [r4/r12-verified] ---
  short8 whi[16], wlo[16];
  {
    const int gate = tr & 3;
    const int u_row = mt * 4 + (tr >> 2);
    const int64_t R = (int64_t)gate * 512 + ug * 8 + u_row;
    const float* wsrc = Whh + R * 512 + q * 8;
#pragma unroll
    for (int kk = 0; kk < 16; ++kk) {
      float4 a = *(const float4*)(wsrc + kk * 32);
      float4 b = *(const float4*)(wsrc + kk * 32 + 4);
      float v[8] = {a.x, a.y, a.z, a.w, b.x, b.y, b.z, b.w};
      ushort8 hi8, lo8;
#pragma unroll
      for (int e = 0; e < 8; ++e) {
        u16 h = f2bf(v[e]);
        hi8[e] = h;
        lo8[e] = f2bf(v[e] - bf2f(h));
      }
      whi[kk] = (short8)hi8;
      wlo[kk] = (short8)lo8;
    }
  }

  // --- W_in from Wp into wlds [r12-verified layout, now all layers] ---
  {
#pragma unroll
    for (int i = 0; i < 16; ++i) {
      int id = tid + i * 256;        // 4096 chunks of 8 u16
      int r = id >> 7;               // 0..31 = mt*16 + tr2
      int p = (id >> 6) & 1;
      int kc = (id & 63) * 8;
      int tr2 = r & 15;
      int grow = (tr2 & 3) * 512 + ug * 8 + ((r >> 4) * 4 + (tr2 >> 2));
      ushort8 v = *(const ushort8*)(Wp + (int64_t)grow * KS + p * 512 + kc);
      *(ushort8*)&wlds[((r * 2 + p) << 9) + (kc ^ ((tr2 & 7) << 3))] = v;
    }
  }
  __syncthreads();

  const int bat = nt * 16 + cb;
  const int ucol = ug * 8 + mt * 4 + q;
  const float b0 = bs[ucol], b1 = bs[512 + ucol], b2 = bs[1024 + ucol],
              b3 = bs[1536 + ucol];
  float cst = 0.f;

  int* fl_own = flags + l * 64;
  int* fl_up = flags + (l - 1) * 64;
  int* fl_dn = flags + (l + 1) * 64;
  const int wibase = (mt * 16 + tr) * 1024;
  const int wswz = (tr & 7) << 3;
  const int hswz = (bat & 7) << 3;
  const int hrb = bat * 1024;  // this lane's staged-row base in hbuf

  for (int ts = 0; ts < NT; ++ts) {
    // --- combined poll: own(ts) / upstream(ts+1) / throttle(ts-8 every 8) ---
    {
      const bool chk_own = (ts > 0);
      const bool chk_up = (l > 0);
      const bool chk_dn = (l < 2) && ((ts & 7) == 0);
      if (chk_own | chk_up | chk_dn) {
        int gd = 0;
        for (;;) {
          int ok = 1;
          if (chk_own) ok &= (ldf(fl_own + lane) >= ts);
          if (chk_up) ok &= (ldf(fl_up + lane) >= ts + 1);
          if (chk_dn) ok &= (ldf(fl_dn + lane) >= ts - 8);
          if (__all(ok)) break;
          __builtin_amdgcn_s_sleep(2);
          if (++gd > (1 << 13)) break;  // anomaly: fail fast to wrong output
        }
      }
    }

    f32x4 acc0 = {0.f, 0.f, 0.f, 0.f};
    f32x4 acc1 = {0.f, 0.f, 0.f, 0.f};
    f32x4 acc2 = {0.f, 0.f, 0.f, 0.f};

    // ---- phase A: recurrent term W_hh * h_l(ts-1), staged via hbuf ----
    if (ts > 0) {
      const u16* src = hring + ((int64_t)(l * RR + ((ts - 1) & (RR - 1))) * NB) * KS;
      uint4 v[16];
#pragma unroll
      for (int i = 0; i < 16; ++i) {
        int c = i * 256 + tid;
        int sb = c >> 7, so = (c & 127) * 8;
        ld16_sc(src + sb * KS + so, v[i]);
      }
      asm volatile("s_waitcnt vmcnt(0)" ::: "memory");
      __builtin_amdgcn_sched_barrier(0);
#pragma unroll
      for (int i = 0; i < 16; ++i) {
        int c = i * 256 + tid;
        int sb = c >> 7, so = (c & 127) * 8;
        *(uint4*)&hbuf[sb * 1024 + (so & 512) + ((so & 511) ^ ((sb & 7) << 3))] = v[i];
      }
      __syncthreads();
#pragma unroll
      for (int kk = 0; kk < 16; ++kk) {
        const int kidx = (kk * 32 + q * 8) ^ hswz;
        short8 hhv = *(const short8*)&hbuf[hrb + kidx];
        short8 hlv = *(const short8*)&hbuf[hrb + 512 + kidx];
        acc0 = __builtin_amdgcn_mfma_f32_16x16x32_bf16(whi[kk], hhv, acc0, 0, 0, 0);
        acc1 = __builtin_amdgcn_mfma_f32_16x16x32_bf16(whi[kk], hlv, acc1, 0, 0, 0);
        acc2 = __builtin_amdgcn_mfma_f32_16x16x32_bf16(wlo[kk], hhv, acc2, 0, 0, 0);
      }
      __syncthreads();  // all phase-A reads done before phase-B overwrites
    }

    // ---- phase B: input term W_in * input(ts), staged via hbuf ----
    {
      const u16* srcb;
      int64_t sstride;
      if (l == 0) {
        srcb = xs + (int64_t)ts * KS;          // batch stride NT*KS
        sstride = (int64_t)NT * KS;
      } else {
        srcb = hring + ((int64_t)((l - 1) * RR + (ts & (RR - 1))) * NB) * KS;
        sstride = KS;                           // contiguous batch rows
      }
      uint4 v[16];
#pragma unroll
      for (int i = 0; i < 16; ++i) {
        int c = i * 256 + tid;
        int sb = c >> 7, so = (c & 127) * 8;
        ld16_sc(srcb + (int64_t)sb * sstride + so, v[i]);
      }
      asm volatile("s_waitcnt vmcnt(0)" ::: "memory");
      __builtin_amdgcn_sched_barrier(0);
#pragma unroll
      for (int i = 0; i < 16; ++i) {
        int c = i * 256 + tid;
        int sb = c >> 7, so = (c & 127) * 8;
        *(uint4*)&hbuf[sb * 1024 + (so & 512) + ((so & 511) ^ ((sb & 7) << 3))] = v[i];
      }
      __syncthreads();
#pragma unroll
      for (int kk = 0; kk < 16; ++kk) {
        const int kidx = (kk * 32 + q * 8) ^ wswz;
        short8 wih = *(const short8*)&wlds[wibase + kidx];        // hi plane
        short8 wil = *(const short8*)&wlds[wibase + 512 + kidx];  // lo plane
        const int xidx = (kk * 32 + q * 8) ^ hswz;
        short8 xhv = *(const short8*)&hbuf[hrb + xidx];
        short8 xlv = *(const short8*)&hbuf[hrb + 512 + xidx];
        acc0 = __builtin_amdgcn_mfma_f32_16x16x32_bf16(wih, xhv, acc0, 0, 0, 0);
        acc1 = __builtin_amdgcn_mfma_f32_16x16x32_bf16(wih, xlv, acc1, 0, 0, 0);
        acc2 = __builtin_amdgcn_mfma_f32_16x16x32_bf16(wil, xhv, acc2, 0, 0, 0);
      }
    }

    float ip = (acc0[0] + acc1[0] + acc2[0]) + b0;
    float fp = (acc0[1] + acc1[1] + acc2[1]) + b1;
    float gg = (acc0[2] + acc1[2] + acc2[2]) + b2;
    float op = (acc0[3] + acc1[3] + acc2[3]) + b3;
    float i_s = sigm(ip), f_s = sigm(fp), g_t = tanh_s(gg), o_s = sigm(op);
    cst = f_s * cst + i_s * g_t;
    float h = o_s * tanh_s(cst);

    u16 hhi = f2bf(h);
    u16 hlo = f2bf(h - bf2f(hhi));
    u16* hw = hring + (((int64_t)(l * RR + (ts & (RR - 1))) * NB + bat)) * KS + ucol;
    st16b_sc(hw, (unsigned)hhi);
    st16b_sc(hw + 512, (unsigned)hlo);
    if (l == 2 && ts == NT - 1) {
      hfinal[bat * 1024 + ucol] = hhi;
      hfinal[bat * 1024 + 512 + ucol] = hlo;
    }
    asm volatile("s_waitcnt vmcnt(0)" ::: "memory");  // h at IC
    __syncthreads();  // all 4 waves done (also fences hbuf for next step)
    if (tid == 0) st32b_sc(fl_own + ug, ts + 1);
  }
}

// out[32,80] = (hi+lo of hfinal) @ W_out^T + b_out
__global__ void k_final(const u16* __restrict__ hfinal, const float* __restrict__ Wout,
                        const float* __restrict__ bout, float* __restrict__ out) {
  const int b = blockIdx.x;
  const int o = threadIdx.x;
  if (o >= 80) return;
  const u16* hp = hfinal + b * 1024;
  float acc = bout[o];
  for (int k = 0; k < 512; ++k)
    acc += (bf2f(hp[k]) + bf2f(hp[512 + k])) * Wout[o * 512 + k];
  out[b * 80 + o] = acc;
}

extern "C" void kernel_launch(void* const* d_in, const int* in_sizes, int n_in,
                              void* d_out, int out_size, void* d_ws, size_t ws_size,
                              hipStream_t stream) {
  const float* X = (const float*)d_in[0];
  const float* Wih[3] = {(const float*)d_in[1], (const float*)d_in[5], (const float*)d_in[9]};
  const float* Whh[3] = {(const float*)d_in[2], (const float*)d_in[6], (const float*)d_in[10]};
  const float* bih[3] = {(const float*)d_in[3], (const float*)d_in[7], (const float*)d_in[11]};
  const float* bhh[3] = {(const float*)d_in[4], (const float*)d_in[8], (const float*)d_in[12]};
  const float* Wout = (const float*)d_in[13];
  const float* bout = (const float*)d_in[14];
  float* out = (float*)d_out;

  char* ws = (char*)d_ws;
  size_t off = 0;
  auto alloc = [&](size_t bytes) {
    char* p = ws + off;
    off = (off + bytes + 255) & ~(size_t)255;
    return p;
  };
  u16* xs = (u16*)alloc((size_t)MROWS * KS * 2);          // 64 MiB
  u16* Wp[3];
  for (int l = 0; l < 3; ++l) Wp[l] = (u16*)alloc((size_t)N4H * KS * 2);  // 4 MiB each
  float* bias[3];
  for (int l = 0; l < 3; ++l) bias[l] = (float*)alloc(N4H * 4);
  u16* hring = (u16*)alloc((size_t)3 * RR * NB * KS * 2); // 3 MiB
  u16* hfinal = (u16*)alloc(NB * 1024 * 2);               // 64 KiB
  int* flags = (int*)alloc(3 * 64 * 4);                   // 768 B
  // total ~79.5 MiB

  hipMemsetAsync(flags, 0, 3 * 64 * 4, stream);
  k_gather_x<<<65536, 256, 0, stream>>>(X, xs);
  for (int l = 0; l < 3; ++l) {
    k_split_w<<<4096, 256, 0, stream>>>(Wih[l], Wp[l]);
    k_bias<<<8, 256, 0, stream>>>(bih[l], bhh[l], bias[l]);
  }

  k_lstm3<<<192, 256, 0, stream>>>(Whh[0], Whh[1], Whh[2],
                                   Wp[0], Wp[1], Wp[2],
                                   bias[0], bias[1], bias[2],
                                   xs, hring, hfinal, flags);

  k_final<<<32, 128, 0, stream>>>(hfinal, Wout, bout, out);
}

// Round 14
// 5337.444 us; speedup vs baseline: 7.4280x; 1.6201x over previous
//
#include <hip/hip_runtime.h>
#include <cstdint>

// ---------------------------------------------------------------------------
// 3-layer LSTM (B=32, T=1024, H=I=512), PyTorch gate order (i,f,g,o).
// ROUND 14: 16-units x 16-batches WG partition + fused dual-operand staging.
// r13 measured step 8.2us = 1.4 fixed + 2048 lines x 2.7ns + ~1 LDS. Lines
// are per-CU staged bytes; halving batches/WG halves both operands ->
// 1024 lines/step. Both operands' loads issue under ONE vmcnt(0) (poll
// already guarantees own h(ts-1) AND upstream h(ts)).
//  - Layer partition: 64 WGs = 32 unit-groups (16 units) x 2 batch-groups
//    (16 batches). Wave w = one 16x16 M-tile (4 units x 4 gates), lane
//    (q=lane>>4, cb=lane&15) owns (unit=ugg*16+w*4+q, batch=bg*16+cb):
//    256 threads = 256 (u,b) pairs, no padding.
//  - Storage: W_hh hi+lo in regs (128 VGPR); W_in hi in LDS (64KB,
//    swizzled), W_in lo in regs (64 VGPR); hbuf 2x32KB. LDS=128KB (1 WG/CU).
//  - Flags per (layer, bg): WG polls only 32 same-bg flags (own + upstream);
//    downstream throttle every 8 steps (ring WAR, RR=16) as r12-verified.
//  - FULL split-bf16 numerics retained (absmax 3.8e-6 expected unchanged).
// Predicted step ~5.0us -> total ~5.5ms (from 8.65).
// ---------------------------------------------------------------------------

typedef unsigned short u16;
typedef short short8 __attribute__((ext_vector_type(8)));
typedef unsigned short ushort8 __attribute__((ext_vector_type(8)));
typedef float f32x4 __attribute__((ext_vector_type(4)));

#define NB 32
#define NT 1024
#define NH 512
#define N4H 2048
#define KS 1024   // stored row: [hi(512) | lo(512)] bf16
#define RR 16     // hring depth (power of 2)
#define MROWS (NB * NT)
#define HBUFB 16384  // u16 offset of operand-B buffer in hbuf

__device__ __forceinline__ u16 f2bf(float f) {
  uint32_t u = __float_as_uint(f);
  uint32_t r = (u + 0x7fffu + ((u >> 16) & 1u)) >> 16;
  return (u16)r;
}
__device__ __forceinline__ float bf2f(u16 h) {
  return __uint_as_float((uint32_t)h << 16);
}
__device__ __forceinline__ float sigm(float x) { return 1.f / (1.f + __expf(-x)); }
__device__ __forceinline__ float tanh_s(float x) {
  float a = fabsf(x);
  float e = __expf(-2.f * a);
  float t = (1.f - e) / (1.f + e);
  return copysignf(t, x);
}

// --- per-instruction device-coherent (IC-level) accessors ---
__device__ __forceinline__ void ld16_sc(const u16* p, uint4& d) {
  asm volatile("global_load_dwordx4 %0, %1, off sc0 sc1" : "=v"(d) : "v"(p));
}
__device__ __forceinline__ int ldf(const int* p) {
  int r;
  asm volatile("global_load_dword %0, %1, off sc0 sc1\n\ts_waitcnt vmcnt(0)"
               : "=v"(r) : "v"(p) : "memory");
  return r;
}
__device__ __forceinline__ void st16b_sc(u16* p, unsigned v) {
  asm volatile("global_store_short %0, %1, off sc0 sc1" :: "v"(p), "v"(v) : "memory");
}
__device__ __forceinline__ void st32b_sc(int* p, int v) {
  asm volatile("global_store_dword %0, %1, off sc0 sc1" :: "v"(p), "v"(v) : "memory");
}

// X [32,4,1024,128] f32 -> xs[n=b*1024+t][hi(512)|lo(512)] bf16
__global__ void k_gather_x(const float* __restrict__ X, u16* __restrict__ xs) {
  int64_t i = (int64_t)blockIdx.x * 256 + threadIdx.x;  // 16,777,216
  int k = (int)(i & 511);
  int t = (int)((i >> 9) & 1023);
  int b = (int)(i >> 19);
  int c = k >> 7, f = k & 127;
  float v = X[(((int64_t)(b * 4 + c) * 1024 + t) << 7) + f];
  u16 hi = f2bf(v);
  u16 lo = f2bf(v - bf2f(hi));
  int64_t n = (int64_t)b * 1024 + t;
  xs[n * KS + k] = hi;
  xs[n * KS + 512 + k] = lo;
}

// W [2048,512] f32 -> Wp[2048][hi(512)|lo(512)] bf16
__global__ void k_split_w(const float* __restrict__ W, u16* __restrict__ Wp) {
  int i = blockIdx.x * 256 + threadIdx.x;  // 1,048,576
  int r = i >> 9, k = i & 511;
  float v = W[i];
  u16 hi = f2bf(v);
  u16 lo = f2bf(v - bf2f(hi));
  Wp[r * KS + k] = hi;
  Wp[r * KS + 512 + k] = lo;
}

__global__ void k_bias(const float* __restrict__ bi, const float* __restrict__ bh,
                       float* __restrict__ bo) {
  int i = blockIdx.x * 256 + threadIdx.x;
  if (i < N4H) bo[i] = bi[i] + bh[i];
}

// ---------------------------------------------------------------------------
// Single-launch pipelined 3-layer LSTM. 192 WGs x 256 thr.
// wg: l=wg>>6; wgl=wg&63; bg=wgl>>5; ugg=wgl&31.
// Wave w: M-tile rows tr=lane&15 -> (gate=tr&3, u_row=tr>>2); lane owns
// (unit=ugg*16+w*4+q, batch=bg*16+cb), q=lane>>4, cb=lane&15.
// Step ts: gates = bias + W_in*input(ts) + W_hh*h_l(ts-1);
//   input = xs(ts) [l=0] or hring[l-1][ts&15] [l>0], batches bg*16..+15.
// Both operands staged to hbuf (A @0, B @HBUFB; 16 rows x 1024 u16 [hi|lo],
// XOR-swz by row&7) in ONE load batch; single vmcnt(0); 2 barriers/step.
// ---------------------------------------------------------------------------
__launch_bounds__(256, 1)
__global__ void k_lstm3(const float* __restrict__ Whh0, const float* __restrict__ Whh1,
                        const float* __restrict__ Whh2,
                        const u16* __restrict__ Wp0, const u16* __restrict__ Wp1,
                        const u16* __restrict__ Wp2,
                        const float* __restrict__ bias0, const float* __restrict__ bias1,
                        const float* __restrict__ bias2,
                        const u16* __restrict__ xs, u16* __restrict__ hring,
                        u16* __restrict__ hfinal, int* __restrict__ flags) {
  __shared__ u16 wlds[32768];  // W_in hi plane: 64 rows x 512, swz
  __shared__ u16 hbuf[32768];  // A @0, B @16384: 16 rows x 1024 [hi|lo], swz
  const int tid = threadIdx.x;
  const int lane = tid & 63;
  const int w = tid >> 6;
  const int wg = blockIdx.x;
  const int l = wg >> 6;
  const int wgl = wg & 63;
  const int bg = wgl >> 5;
  const int ugg = wgl & 31;
  const int q = lane >> 4;
  const int cb = lane & 15;
  const int tr = lane & 15;

  const float* Whh = (l == 0) ? Whh0 : (l == 1) ? Whh1 : Whh2;
  const u16* Wp = (l == 0) ? Wp0 : (l == 1) ? Wp1 : Wp2;
  const float* bs = (l == 0) ? bias0 : (l == 1) ? bias1 : bias2;

  // this lane's A-row (shared by W_hh and W_in): gate=tr&3, u_row=tr>>2
  const int64_t grow = (int64_t)(tr & 3) * 512 + ugg * 16 + w * 4 + (tr >> 2);

  // --- W_hh frags (split bf16 on the fly) into registers ---
  short8 whi[16], wlo[16];
  {
    const float* wsrc = Whh + grow * 512 + q * 8;
#pragma unroll
    for (int kk = 0; kk < 16; ++kk) {
      float4 a = *(const float4*)(wsrc + kk * 32);
      float4 b = *(const float4*)(wsrc + kk * 32 + 4);
      float v[8] = {a.x, a.y, a.z, a.w, b.x, b.y, b.z, b.w};
      ushort8 hi8, lo8;
#pragma unroll
      for (int e = 0; e < 8; ++e) {
        u16 h = f2bf(v[e]);
        hi8[e] = h;
        lo8[e] = f2bf(v[e] - bf2f(h));
      }
      whi[kk] = (short8)hi8;
      wlo[kk] = (short8)lo8;
    }
  }

  // --- W_in lo plane into registers ---
  short8 wil[16];
  {
    const u16* wsrc = Wp + grow * KS + 512 + q * 8;
#pragma unroll
    for (int kk = 0; kk < 16; ++kk) wil[kk] = *(const short8*)(wsrc + kk * 32);
  }

  // --- W_in hi plane into wlds: row r=w*16+tr at r*512, elems ^((tr&7)<<3)
  {
#pragma unroll
    for (int i = 0; i < 16; ++i) {
      int c = tid + i * 256;          // 4096 chunks of 8 u16
      int r = c >> 6;                 // 0..63
      int kc = (c & 63) * 8;          // 0..504
      int tr2 = r & 15;
      int64_t gr = (int64_t)(tr2 & 3) * 512 + ugg * 16 + (r >> 4) * 4 + (tr2 >> 2);
      ushort8 v = *(const ushort8*)(Wp + gr * KS + kc);
      *(ushort8*)&wlds[r * 512 + (kc ^ ((tr2 & 7) << 3))] = v;
    }
  }
  __syncthreads();

  const int bat = bg * 16 + cb;              // this lane's batch
  const int ucol = ugg * 16 + w * 4 + q;     // this lane's unit
  const float b0 = bs[ucol], b1 = bs[512 + ucol], b2 = bs[1024 + ucol],
              b3 = bs[1536 + ucol];
  float cst = 0.f;

  int* fl_own = flags + l * 64 + bg * 32;
  int* fl_up = flags + (l - 1) * 64 + bg * 32;
  int* fl_dn = flags + (l + 1) * 64 + bg * 32;
  const int wrow = (w * 16 + tr) * 512;      // lane's W_in-hi LDS row base
  const int wswz = (tr & 7) << 3;
  const int hswz = (cb & 7) << 3;
  const int hrbA = cb * 1024;
  const int hrbB = HBUFB + cb * 1024;

  for (int ts = 0; ts < NT; ++ts) {
    // --- poll: own(>=ts) / upstream(>=ts+1) / downstream throttle ---
    {
      const bool chk_own = (ts > 0);
      const bool chk_up = (l > 0);
      const bool chk_dn = (l < 2) && ((ts & 7) == 0);
      if (chk_own | chk_up | chk_dn) {
        int gd = 0;
        for (;;) {
          int ok = 1;
          if (chk_own) ok &= (ldf(fl_own + (lane & 31)) >= ts);
          if (chk_up) ok &= (ldf(fl_up + (lane & 31)) >= ts + 1);
          if (chk_dn) ok &= (ldf(fl_dn + (lane & 31)) >= ts - 8);
          if (__all(ok)) break;
          __builtin_amdgcn_s_sleep(2);
          if (++gd > (1 << 13)) break;  // anomaly: fail fast to wrong output
        }
      }
    }

    // --- fused staging: issue A (own h(ts-1)) + B (input(ts)) loads ---
    uint4 v[16];
    const u16* srcA = hring + ((int64_t)(l * RR + ((ts - 1) & (RR - 1))) * NB
                               + bg * 16) * KS;
    if (ts > 0) {
#pragma unroll
      for (int i = 0; i < 8; ++i) {
        int c = tid + i * 256;
        int sb = c >> 7, so = (c & 127) * 8;
        ld16_sc(srcA + sb * KS + so, v[i]);
      }
    }
    if (l == 0) {
      const u16* srcB = xs + ((int64_t)(bg * 16) * NT + ts) * KS;
#pragma unroll
      for (int i = 0; i < 8; ++i) {
        int c = tid + i * 256;
        int sb = c >> 7, so = (c & 127) * 8;
        ld16_sc(srcB + (int64_t)sb * NT * KS + so, v[8 + i]);
      }
    } else {
      const u16* srcB = hring + ((int64_t)((l - 1) * RR + (ts & (RR - 1))) * NB
                                 + bg * 16) * KS;
#pragma unroll
      for (int i = 0; i < 8; ++i) {
        int c = tid + i * 256;
        int sb = c >> 7, so = (c & 127) * 8;
        ld16_sc(srcB + sb * KS + so, v[8 + i]);
      }
    }
    asm volatile("s_waitcnt vmcnt(0)" ::: "memory");
    __builtin_amdgcn_sched_barrier(0);

    // --- LDS writes (swizzled) ---
    if (ts > 0) {
#pragma unroll
      for (int i = 0; i < 8; ++i) {
        int c = tid + i * 256;
        int sb = c >> 7, so = (c & 127) * 8;
        *(uint4*)&hbuf[sb * 1024 + (so & 512) + ((so & 511) ^ ((sb & 7) << 3))] = v[i];
      }
    }
#pragma unroll
    for (int i = 0; i < 8; ++i) {
      int c = tid + i * 256;
      int sb = c >> 7, so = (c & 127) * 8;
      *(uint4*)&hbuf[HBUFB + sb * 1024 + (so & 512) + ((so & 511) ^ ((sb & 7) << 3))] = v[8 + i];
    }
    __syncthreads();

    f32x4 acc0 = {0.f, 0.f, 0.f, 0.f};
    f32x4 acc1 = {0.f, 0.f, 0.f, 0.f};
    f32x4 acc2 = {0.f, 0.f, 0.f, 0.f};

    // --- MFMA block A: W_hh (regs) x h_l(ts-1) ---
    if (ts > 0) {
#pragma unroll
      for (int kk = 0; kk < 16; ++kk) {
        const int kidx = (kk * 32 + q * 8) ^ hswz;
        short8 hhv = *(const short8*)&hbuf[hrbA + kidx];
        short8 hlv = *(const short8*)&hbuf[hrbA + 512 + kidx];
        acc0 = __builtin_amdgcn_mfma_f32_16x16x32_bf16(whi[kk], hhv, acc0, 0, 0, 0);
        acc1 = __builtin_amdgcn_mfma_f32_16x16x32_bf16(whi[kk], hlv, acc1, 0, 0, 0);
        acc2 = __builtin_amdgcn_mfma_f32_16x16x32_bf16(wlo[kk], hhv, acc2, 0, 0, 0);
      }
    }

    // --- MFMA block B: W_in (hi LDS, lo regs) x input(ts) ---
#pragma unroll
    for (int kk = 0; kk < 16; ++kk) {
      const int kv = kk * 32 + q * 8;
      short8 wih = *(const short8*)&wlds[wrow + (kv ^ wswz)];
      const int xidx = kv ^ hswz;
      short8 xhv = *(const short8*)&hbuf[hrbB + xidx];
      short8 xlv = *(const short8*)&hbuf[hrbB + 512 + xidx];
      acc0 = __builtin_amdgcn_mfma_f32_16x16x32_bf16(wih, xhv, acc0, 0, 0, 0);
      acc1 = __builtin_amdgcn_mfma_f32_16x16x32_bf16(wih, xlv, acc1, 0, 0, 0);
      acc2 = __builtin_amdgcn_mfma_f32_16x16x32_bf16(wil[kk], xhv, acc2, 0, 0, 0);
    }

    float ip = (acc0[0] + acc1[0] + acc2[0]) + b0;
    float fp = (acc0[1] + acc1[1] + acc2[1]) + b1;
    float gg = (acc0[2] + acc1[2] + acc2[2]) + b2;
    float op = (acc0[3] + acc1[3] + acc2[3]) + b3;
    float i_s = sigm(ip), f_s = sigm(fp), g_t = tanh_s(gg), o_s = sigm(op);
    cst = f_s * cst + i_s * g_t;
    float h = o_s * tanh_s(cst);

    u16 hhi = f2bf(h);
    u16 hlo = f2bf(h - bf2f(hhi));
    u16* hw = hring + ((int64_t)(l * RR + (ts & (RR - 1))) * NB + bat) * KS + ucol;
    st16b_sc(hw, (unsigned)hhi);
    st16b_sc(hw + 512, (unsigned)hlo);
    if (l == 2 && ts == NT - 1) {
      hfinal[bat * 1024 + ucol] = hhi;
      hfinal[bat * 1024 + 512 + ucol] = hlo;
    }
    asm volatile("s_waitcnt vmcnt(0)" ::: "memory");  // h at IC
    __syncthreads();  // all waves done (also fences hbuf for next step)
    if (tid == 0) st32b_sc(flags + l * 64 + bg * 32 + ugg, ts + 1);
  }
}

// out[32,80] = (hi+lo of hfinal) @ W_out^T + b_out
__global__ void k_final(const u16* __restrict__ hfinal, const float* __restrict__ Wout,
                        const float* __restrict__ bout, float* __restrict__ out) {
  const int b = blockIdx.x;
  const int o = threadIdx.x;
  if (o >= 80) return;
  const u16* hp = hfinal + b * 1024;
  float acc = bout[o];
  for (int k = 0; k < 512; ++k)
    acc += (bf2f(hp[k]) + bf2f(hp[512 + k])) * Wout[o * 512 + k];
  out[b * 80 + o] = acc;
}

extern "C" void kernel_launch(void* const* d_in, const int* in_sizes, int n_in,
                              void* d_out, int out_size, void* d_ws, size_t ws_size,
                              hipStream_t stream) {
  const float* X = (const float*)d_in[0];
  const float* Wih[3] = {(const float*)d_in[1], (const float*)d_in[5], (const float*)d_in[9]};
  const float* Whh[3] = {(const float*)d_in[2], (const float*)d_in[6], (const float*)d_in[10]};
  const float* bih[3] = {(const float*)d_in[3], (const float*)d_in[7], (const float*)d_in[11]};
  const float* bhh[3] = {(const float*)d_in[4], (const float*)d_in[8], (const float*)d_in[12]};
  const float* Wout = (const float*)d_in[13];
  const float* bout = (const float*)d_in[14];
  float* out = (float*)d_out;

  char* ws = (char*)d_ws;
  size_t off = 0;
  auto alloc = [&](size_t bytes) {
    char* p = ws + off;
    off = (off + bytes + 255) & ~(size_t)255;
    return p;
  };
  u16* xs = (u16*)alloc((size_t)MROWS * KS * 2);          // 64 MiB
  u16* Wp[3];
  for (int l = 0; l < 3; ++l) Wp[l] = (u16*)alloc((size_t)N4H * KS * 2);  // 4 MiB each
  float* bias[3];
  for (int l = 0; l < 3; ++l) bias[l] = (float*)alloc(N4H * 4);
  u16* hring = (u16*)alloc((size_t)3 * RR * NB * KS * 2); // 3 MiB
  u16* hfinal = (u16*)alloc(NB * 1024 * 2);               // 64 KiB
  int* flags = (int*)alloc(3 * 64 * 4);                   // 768 B
  // total ~79.5 MiB

  hipMemsetAsync(flags, 0, 3 * 64 * 4, stream);
  k_gather_x<<<65536, 256, 0, stream>>>(X, xs);
  for (int l = 0; l < 3; ++l) {
    k_split_w<<<4096, 256, 0, stream>>>(Wih[l], Wp[l]);
    k_bias<<<8, 256, 0, stream>>>(bih[l], bhh[l], bias[l]);
  }

  k_lstm3<<<192, 256, 0, stream>>>(Whh[0], Whh[1], Whh[2],
                                   Wp[0], Wp[1], Wp[2],
                                   bias[0], bias[1], bias[2],
                                   xs, hring, hfinal, flags);

  k_final<<<32, 128, 0, stream>>>(hfinal, Wout, bout, out);
}

// Round 15
// 3872.647 us; speedup vs baseline: 10.2375x; 1.3782x over previous
//
#include <hip/hip_runtime.h>
#include <cstdint>

// ---------------------------------------------------------------------------
// 3-layer LSTM (B=32, T=1024, H=I=512), PyTorch gate order (i,f,g,o).
// ROUND 15: single-plane FP16 pipeline (from r14's verified structure).
// r14 validated: step = 1.4us fixed + 2.7ns/line + ~1us LDS; lines dominated.
// fp16 (11-bit mantissa) single plane replaces split-bf16 (hi+lo):
//   - h is tanh-bounded, x~N(0,1): both in fp16 range; predicted output
//     absmax ~3e-4 vs 1.39e-3 threshold (~4.5x margin).
//   - Exchange rows 2KB -> 1KB: staged lines 1024 -> 512/step.
//   - MFMA 96 -> 32/step (mfma_f32_16x16x32_f16, exact f32 accum);
//     LDS reads 80 -> 48; staged loads 16 -> 8 uint4/thread.
//   - W_in fp16 in LDS (64KB); W_hh fp16 in regs (64 VGPR); hbuf 2x16KB.
// Partition/staging/swizzle/flag protocol BYTE-IDENTICAL to r14 (verified).
// Fallback if absmax fails: revert to r14 split-bf16 exchange.
// Predicted: step ~3.3us, total ~3.7ms (from 5.34).
// ---------------------------------------------------------------------------

typedef unsigned short u16;
typedef _Float16 f16;
typedef f16 f16x8 __attribute__((ext_vector_type(8)));
typedef unsigned short ushort8 __attribute__((ext_vector_type(8)));
typedef float f32x4 __attribute__((ext_vector_type(4)));

#define NB 32
#define NT 1024
#define NH 512
#define N4H 2048
#define RR 16     // hring depth (power of 2)
#define MROWS (NB * NT)
#define HBUFB 8192  // u16 offset of operand-B buffer in hbuf

__device__ __forceinline__ float sigm(float x) { return 1.f / (1.f + __expf(-x)); }
__device__ __forceinline__ float tanh_s(float x) {
  float a = fabsf(x);
  float e = __expf(-2.f * a);
  float t = (1.f - e) / (1.f + e);
  return copysignf(t, x);
}

// --- per-instruction device-coherent (IC-level) accessors ---
__device__ __forceinline__ void ld16_sc(const u16* p, uint4& d) {
  asm volatile("global_load_dwordx4 %0, %1, off sc0 sc1" : "=v"(d) : "v"(p));
}
__device__ __forceinline__ int ldf(const int* p) {
  int r;
  asm volatile("global_load_dword %0, %1, off sc0 sc1\n\ts_waitcnt vmcnt(0)"
               : "=v"(r) : "v"(p) : "memory");
  return r;
}
__device__ __forceinline__ void st16b_sc(u16* p, unsigned v) {
  asm volatile("global_store_short %0, %1, off sc0 sc1" :: "v"(p), "v"(v) : "memory");
}
__device__ __forceinline__ void st32b_sc(int* p, int v) {
  asm volatile("global_store_dword %0, %1, off sc0 sc1" :: "v"(p), "v"(v) : "memory");
}

// X [32,4,1024,128] f32 -> xs[n=b*1024+t][512] fp16
__global__ void k_gather_x(const float* __restrict__ X, u16* __restrict__ xs) {
  int64_t i = (int64_t)blockIdx.x * 256 + threadIdx.x;  // 16,777,216
  int k = (int)(i & 511);
  int t = (int)((i >> 9) & 1023);
  int b = (int)(i >> 19);
  int c = k >> 7, f = k & 127;
  float v = X[(((int64_t)(b * 4 + c) * 1024 + t) << 7) + f];
  f16 hv = (f16)v;
  xs[((int64_t)b * 1024 + t) * 512 + k] = *(u16*)&hv;
}

// W [2048,512] f32 -> Wp[2048][512] fp16
__global__ void k_split_w(const float* __restrict__ W, u16* __restrict__ Wp) {
  int i = blockIdx.x * 256 + threadIdx.x;  // 1,048,576
  f16 hv = (f16)W[i];
  Wp[i] = *(u16*)&hv;
}

__global__ void k_bias(const float* __restrict__ bi, const float* __restrict__ bh,
                       float* __restrict__ bo) {
  int i = blockIdx.x * 256 + threadIdx.x;
  if (i < N4H) bo[i] = bi[i] + bh[i];
}

// ---------------------------------------------------------------------------
// Single-launch pipelined 3-layer LSTM, fp16. 192 WGs x 256 thr.
// wg: l=wg>>6; wgl=wg&63; bg=wgl>>5; ugg=wgl&31.  [r14-verified partition]
// Wave w: M-tile rows tr=lane&15 -> (gate=tr&3, u_row=tr>>2); lane owns
// (unit=ugg*16+w*4+q, batch=bg*16+cb), q=lane>>4, cb=lane&15.
// Step ts: gates = bias + W_in*input(ts) + W_hh*h_l(ts-1);
//   input = xs(ts) [l=0] or hring[l-1][ts&15] [l>0], batches bg*16..+15.
// hbuf: A @0, B @HBUFB; 16 rows x 512 f16, XOR-swz by (row&7)<<3.
// wlds: W_in row r=w*16+tr at r*512 f16, elems swz by ((tr&7)<<3).
// Flags per (layer,bg): poll own>=ts, up>=ts+1, dn throttle every 8 steps
// (ring WAR, RR=16) -- protocol identical to r12/r13/r14 (verified).
// ---------------------------------------------------------------------------
__launch_bounds__(256, 1)
__global__ void k_lstm3(const float* __restrict__ Whh0, const float* __restrict__ Whh1,
                        const float* __restrict__ Whh2,
                        const u16* __restrict__ Wp0, const u16* __restrict__ Wp1,
                        const u16* __restrict__ Wp2,
                        const float* __restrict__ bias0, const float* __restrict__ bias1,
                        const float* __restrict__ bias2,
                        const u16* __restrict__ xs, u16* __restrict__ hring,
                        u16* __restrict__ hfinal, int* __restrict__ flags) {
  __shared__ u16 wlds[32768];  // W_in fp16: 64 rows x 512, swz (64KB)
  __shared__ u16 hbuf[16384];  // A @0, B @8192: 16 rows x 512 f16, swz (32KB)
  const int tid = threadIdx.x;
  const int lane = tid & 63;
  const int w = tid >> 6;
  const int wg = blockIdx.x;
  const int l = wg >> 6;
  const int wgl = wg & 63;
  const int bg = wgl >> 5;
  const int ugg = wgl & 31;
  const int q = lane >> 4;
  const int cb = lane & 15;
  const int tr = lane & 15;

  const float* Whh = (l == 0) ? Whh0 : (l == 1) ? Whh1 : Whh2;
  const u16* Wp = (l == 0) ? Wp0 : (l == 1) ? Wp1 : Wp2;
  const float* bs = (l == 0) ? bias0 : (l == 1) ? bias1 : bias2;

  // this lane's A-row: gate=tr&3, u_row=tr>>2
  const int64_t grow = (int64_t)(tr & 3) * 512 + ugg * 16 + w * 4 + (tr >> 2);

  // --- W_hh fp16 frags into registers (64 VGPR) ---
  f16x8 whh[16];
  {
    const float* wsrc = Whh + grow * 512 + q * 8;
#pragma unroll
    for (int kk = 0; kk < 16; ++kk) {
      float4 a = *(const float4*)(wsrc + kk * 32);
      float4 b = *(const float4*)(wsrc + kk * 32 + 4);
      f16x8 hv;
      hv[0] = (f16)a.x; hv[1] = (f16)a.y; hv[2] = (f16)a.z; hv[3] = (f16)a.w;
      hv[4] = (f16)b.x; hv[5] = (f16)b.y; hv[6] = (f16)b.z; hv[7] = (f16)b.w;
      whh[kk] = hv;
    }
  }

  // --- W_in fp16 into wlds: row r=w*16+tr at r*512, elems ^((tr&7)<<3) ---
  {
#pragma unroll
    for (int i = 0; i < 16; ++i) {
      int c = tid + i * 256;          // 4096 chunks of 8 f16
      int r = c >> 6;                 // 0..63
      int kc = (c & 63) * 8;          // 0..504
      int tr2 = r & 15;
      int64_t gr = (int64_t)(tr2 & 3) * 512 + ugg * 16 + (r >> 4) * 4 + (tr2 >> 2);
      ushort8 v = *(const ushort8*)(Wp + gr * 512 + kc);
      *(ushort8*)&wlds[r * 512 + (kc ^ ((tr2 & 7) << 3))] = v;
    }
  }
  __syncthreads();

  const int bat = bg * 16 + cb;              // this lane's batch
  const int ucol = ugg * 16 + w * 4 + q;     // this lane's unit
  const float b0 = bs[ucol], b1 = bs[512 + ucol], b2 = bs[1024 + ucol],
              b3 = bs[1536 + ucol];
  float cst = 0.f;

  int* fl_own = flags + l * 64 + bg * 32;
  int* fl_up = flags + (l - 1) * 64 + bg * 32;
  int* fl_dn = flags + (l + 1) * 64 + bg * 32;
  const int wrow = (w * 16 + tr) * 512;      // lane's W_in LDS row base
  const int wswz = (tr & 7) << 3;
  const int hswz = (cb & 7) << 3;
  const int hrbA = cb * 512;
  const int hrbB = HBUFB + cb * 512;

  for (int ts = 0; ts < NT; ++ts) {
    // --- poll: own(>=ts) / upstream(>=ts+1) / downstream throttle ---
    {
      const bool chk_own = (ts > 0);
      const bool chk_up = (l > 0);
      const bool chk_dn = (l < 2) && ((ts & 7) == 0);
      if (chk_own | chk_up | chk_dn) {
        int gd = 0;
        for (;;) {
          int ok = 1;
          if (chk_own) ok &= (ldf(fl_own + (lane & 31)) >= ts);
          if (chk_up) ok &= (ldf(fl_up + (lane & 31)) >= ts + 1);
          if (chk_dn) ok &= (ldf(fl_dn + (lane & 31)) >= ts - 8);
          if (__all(ok)) break;
          __builtin_amdgcn_s_sleep(2);
          if (++gd > (1 << 13)) break;  // anomaly: fail fast to wrong output
        }
      }
    }

    // --- fused staging: A (own h(ts-1)) + B (input(ts)), one vmcnt(0) ---
    uint4 v[8];
    if (ts > 0) {
      const u16* srcA = hring + ((int64_t)(l * RR + ((ts - 1) & (RR - 1))) * NB
                                 + bg * 16) * 512;
#pragma unroll
      for (int i = 0; i < 4; ++i) {
        int c = tid + i * 256;
        int sb = c >> 6, so = (c & 63) * 8;
        ld16_sc(srcA + sb * 512 + so, v[i]);
      }
    }
    if (l == 0) {
      const u16* srcB = xs + ((int64_t)(bg * 16) * NT + ts) * 512;
#pragma unroll
      for (int i = 0; i < 4; ++i) {
        int c = tid + i * 256;
        int sb = c >> 6, so = (c & 63) * 8;
        ld16_sc(srcB + (int64_t)sb * NT * 512 + so, v[4 + i]);
      }
    } else {
      const u16* srcB = hring + ((int64_t)((l - 1) * RR + (ts & (RR - 1))) * NB
                                 + bg * 16) * 512;
#pragma unroll
      for (int i = 0; i < 4; ++i) {
        int c = tid + i * 256;
        int sb = c >> 6, so = (c & 63) * 8;
        ld16_sc(srcB + sb * 512 + so, v[4 + i]);
      }
    }
    asm volatile("s_waitcnt vmcnt(0)" ::: "memory");
    __builtin_amdgcn_sched_barrier(0);

    // --- LDS writes (swizzled; conflict-free: 1KB contiguous per wave) ---
    if (ts > 0) {
#pragma unroll
      for (int i = 0; i < 4; ++i) {
        int c = tid + i * 256;
        int sb = c >> 6, so = (c & 63) * 8;
        *(uint4*)&hbuf[sb * 512 + (so ^ ((sb & 7) << 3))] = v[i];
      }
    }
#pragma unroll
    for (int i = 0; i < 4; ++i) {
      int c = tid + i * 256;
      int sb = c >> 6, so = (c & 63) * 8;
      *(uint4*)&hbuf[HBUFB + sb * 512 + (so ^ ((sb & 7) << 3))] = v[4 + i];
    }
    __syncthreads();

    f32x4 acc = {0.f, 0.f, 0.f, 0.f};

    // --- MFMA block A: W_hh (regs) x h_l(ts-1) ---
    if (ts > 0) {
#pragma unroll
      for (int kk = 0; kk < 16; ++kk) {
        const int kidx = (kk * 32 + q * 8) ^ hswz;
        f16x8 hv = *(const f16x8*)&hbuf[hrbA + kidx];
        acc = __builtin_amdgcn_mfma_f32_16x16x32_f16(whh[kk], hv, acc, 0, 0, 0);
      }
    }

    // --- MFMA block B: W_in (LDS) x input(ts) ---
#pragma unroll
    for (int kk = 0; kk < 16; ++kk) {
      const int kv = kk * 32 + q * 8;
      f16x8 wv = *(const f16x8*)&wlds[wrow + (kv ^ wswz)];
      f16x8 xv = *(const f16x8*)&hbuf[hrbB + (kv ^ hswz)];
      acc = __builtin_amdgcn_mfma_f32_16x16x32_f16(wv, xv, acc, 0, 0, 0);
    }

    float ip = acc[0] + b0;
    float fp = acc[1] + b1;
    float gg = acc[2] + b2;
    float op = acc[3] + b3;
    float i_s = sigm(ip), f_s = sigm(fp), g_t = tanh_s(gg), o_s = sigm(op);
    cst = f_s * cst + i_s * g_t;
    float h = o_s * tanh_s(cst);

    f16 hf = (f16)h;
    u16 hbits = *(u16*)&hf;
    u16* hw = hring + ((int64_t)(l * RR + (ts & (RR - 1))) * NB + bat) * 512 + ucol;
    st16b_sc(hw, (unsigned)hbits);
    if (l == 2 && ts == NT - 1) hfinal[bat * 512 + ucol] = hbits;
    asm volatile("s_waitcnt vmcnt(0)" ::: "memory");  // h at IC
    __syncthreads();  // all waves done (also fences hbuf for next step)
    if (tid == 0) st32b_sc(flags + l * 64 + bg * 32 + ugg, ts + 1);
  }
}

// out[32,80] = hfinal(fp16) @ W_out^T + b_out
__global__ void k_final(const u16* __restrict__ hfinal, const float* __restrict__ Wout,
                        const float* __restrict__ bout, float* __restrict__ out) {
  const int b = blockIdx.x;
  const int o = threadIdx.x;
  if (o >= 80) return;
  const u16* hp = hfinal + b * 512;
  float acc = bout[o];
  for (int k = 0; k < 512; ++k) {
    f16 hv = *(const f16*)&hp[k];
    acc += (float)hv * Wout[o * 512 + k];
  }
  out[b * 80 + o] = acc;
}

extern "C" void kernel_launch(void* const* d_in, const int* in_sizes, int n_in,
                              void* d_out, int out_size, void* d_ws, size_t ws_size,
                              hipStream_t stream) {
  const float* X = (const float*)d_in[0];
  const float* Wih[3] = {(const float*)d_in[1], (const float*)d_in[5], (const float*)d_in[9]};
  const float* Whh[3] = {(const float*)d_in[2], (const float*)d_in[6], (const float*)d_in[10]};
  const float* bih[3] = {(const float*)d_in[3], (const float*)d_in[7], (const float*)d_in[11]};
  const float* bhh[3] = {(const float*)d_in[4], (const float*)d_in[8], (const float*)d_in[12]};
  const float* Wout = (const float*)d_in[13];
  const float* bout = (const float*)d_in[14];
  float* out = (float*)d_out;

  char* ws = (char*)d_ws;
  size_t off = 0;
  auto alloc = [&](size_t bytes) {
    char* p = ws + off;
    off = (off + bytes + 255) & ~(size_t)255;
    return p;
  };
  u16* xs = (u16*)alloc((size_t)MROWS * 512 * 2);          // 32 MiB
  u16* Wp[3];
  for (int l = 0; l < 3; ++l) Wp[l] = (u16*)alloc((size_t)N4H * 512 * 2);  // 2 MiB each
  float* bias[3];
  for (int l = 0; l < 3; ++l) bias[l] = (float*)alloc(N4H * 4);
  u16* hring = (u16*)alloc((size_t)3 * RR * NB * 512 * 2); // 1.5 MiB
  u16* hfinal = (u16*)alloc(NB * 512 * 2);                 // 32 KiB
  int* flags = (int*)alloc(3 * 64 * 4);                    // 768 B
  // total ~39.6 MiB

  hipMemsetAsync(flags, 0, 3 * 64 * 4, stream);
  k_gather_x<<<65536, 256, 0, stream>>>(X, xs);
  for (int l = 0; l < 3; ++l) {
    k_split_w<<<4096, 256, 0, stream>>>(Wih[l], Wp[l]);
    k_bias<<<8, 256, 0, stream>>>(bih[l], bhh[l], bias[l]);
  }

  k_lstm3<<<192, 256, 0, stream>>>(Whh[0], Whh[1], Whh[2],
                                   Wp[0], Wp[1], Wp[2],
                                   bias[0], bias[1], bias[2],
                                   xs, hring, hfinal, flags);

  k_final<<<32, 128, 0, stream>>>(hfinal, Wout, bout, out);
}